// Round 1
// baseline (1377.732 us; speedup 1.0000x reference)
//
#include <hip/hip_runtime.h>
#include <math.h>

// Problem constants
#define BB 4
#define CC 128
#define NN 4096      // H*W
#define DD 256
#define INNER 512
#define FFD 1024
#define PP 4
#define LL 2
#define NT 8
#define SS 1024      // NN/PP
#define SCALE 0.0625f // 1/sqrt(256)

template<int NW>
__device__ inline float block_sum(float v, float* sbuf){
  #pragma unroll
  for (int mk=32; mk; mk>>=1) v += __shfl_xor(v, mk);
  int w = threadIdx.x>>6;
  if ((threadIdx.x&63)==0) sbuf[w]=v;
  __syncthreads();
  float r = 0.f;
  #pragma unroll
  for (int k=0;k<NW;k++) r += sbuf[k];
  __syncthreads();
  return r;
}

// K1: tokens = LN(x(1x1conv)proj_w + proj_b).  16 tokens per 256-thread block.
__global__ __launch_bounds__(256) void proj_ln_kernel(
    const float* __restrict__ x, const float* __restrict__ proj_w,
    const float* __restrict__ proj_b, const float* __restrict__ lnp_g,
    const float* __restrict__ lnp_b, float* __restrict__ tokens)
{
  int b  = blockIdx.x >> 8;          // 256 blocks per batch
  int n0 = (blockIdx.x & 255) * 16;
  int tid = threadIdx.x;
  __shared__ float xs[16][132];
  __shared__ float ys[16][260];
  __shared__ float mu_s[16], rs_s[16];
  #pragma unroll
  for (int i=0;i<8;i++){
    int l = tid + i*256;
    int t = l & 15, c = l >> 4;
    xs[t][c] = x[(long)(b*CC + c)*NN + n0 + t];
  }
  __syncthreads();
  float acc[16];
  #pragma unroll
  for (int t=0;t<16;t++) acc[t]=0.f;
  for (int c=0;c<CC;c++){
    float wv = proj_w[c*DD + tid];
    #pragma unroll
    for (int t=0;t<16;t++) acc[t] = fmaf(xs[t][c], wv, acc[t]);
  }
  float pb = proj_b[tid];
  #pragma unroll
  for (int t=0;t<16;t++) ys[t][tid] = acc[t] + pb;
  __syncthreads();
  int w = tid>>6, lane = tid&63;
  for (int k=0;k<4;k++){
    int t = w*4+k;
    float s = ys[t][lane] + ys[t][lane+64] + ys[t][lane+128] + ys[t][lane+192];
    #pragma unroll
    for (int mk=32; mk; mk>>=1) s += __shfl_xor(s, mk);
    float mu = s*(1.0f/256.0f);
    float d0=ys[t][lane]-mu, d1=ys[t][lane+64]-mu, d2=ys[t][lane+128]-mu, d3=ys[t][lane+192]-mu;
    float q = d0*d0+d1*d1+d2*d2+d3*d3;
    #pragma unroll
    for (int mk=32; mk; mk>>=1) q += __shfl_xor(q, mk);
    if (lane==0){ mu_s[t]=mu; rs_s[t]=rsqrtf(q*(1.0f/256.0f)+1e-5f); }
  }
  __syncthreads();
  float g = lnp_g[tid], be = lnp_b[tid];
  #pragma unroll
  for (int t=0;t<16;t++){
    tokens[((long)(b*NN + n0 + t))*DD + tid] = (ys[t][tid]-mu_s[t])*rs_s[t]*g + be;
  }
}

// K2a: scorer k = m@sk_w + sk_b  (B,NT,D);  v = m@sv_w + sv_b (B,NT)
__global__ __launch_bounds__(256) void scorer_kv_kernel(
    const float* __restrict__ m, const float* __restrict__ sk_w,
    const float* __restrict__ sk_b, const float* __restrict__ sv_w,
    const float* __restrict__ sv_b, float* __restrict__ ksc, float* __restrict__ vsc)
{
  int bj = blockIdx.x;               // B*NT = 32
  int d = threadIdx.x;
  __shared__ float ms[256];
  __shared__ float sbuf[4];
  ms[d] = m[bj*DD + d];
  __syncthreads();
  float acc=0.f;
  for(int c=0;c<DD;c++) acc = fmaf(ms[c], sk_w[c*DD + d], acc);
  ksc[bj*DD + d] = acc + sk_b[d];
  float sv = block_sum<4>(ms[d]*sv_w[d], sbuf);
  if(d==0) vsc[bj] = sv + sv_b[0];
}

// K2b: per-token score via tiny cross-attn (softmax over 8 memory slots)
__global__ __launch_bounds__(256) void scores_kernel(
    const float* __restrict__ tokens, const float* __restrict__ sq_w,
    const float* __restrict__ sq_b, const float* __restrict__ ksc,
    const float* __restrict__ vsc, float* __restrict__ scores)
{
  int b  = blockIdx.x >> 8;
  int t0 = (blockIdx.x & 255) * 16;
  int tid = threadIdx.x;
  __shared__ float ts[16][260];
  __shared__ float lg[16][8];
  for (int t=0;t<16;t++) ts[t][tid] = tokens[((long)(b*NN + t0 + t))*DD + tid];
  __syncthreads();
  float qa[16];
  #pragma unroll
  for(int t=0;t<16;t++) qa[t]=0.f;
  for(int c=0;c<DD;c++){
    float w = sq_w[c*DD + tid];
    #pragma unroll
    for(int t=0;t<16;t++) qa[t] = fmaf(ts[t][c], w, qa[t]);
  }
  __syncthreads();
  float qb = sq_b[tid];
  for(int t=0;t<16;t++) ts[t][tid] = qa[t] + qb;
  __syncthreads();
  if (tid < 128){
    int t = tid>>3, j = tid&7;
    const float* kk = ksc + (b*NT + j)*DD;
    float acc=0.f;
    for(int c=0;c<DD;c++) acc = fmaf(ts[t][c], kk[c], acc);
    lg[t][j] = acc * SCALE;
  }
  __syncthreads();
  if (tid < 16){
    float mx=-1e30f;
    for(int j=0;j<NT;j++) mx=fmaxf(mx,lg[tid][j]);
    float s=0.f, sc=0.f;
    for(int j=0;j<NT;j++){ float e=__expf(lg[tid][j]-mx); s+=e; sc+=e*vsc[b*NT+j]; }
    scores[b*NN + t0 + tid] = sc/s;
  }
}

// K3: rank = #{s_j > s_i} + #{j<i: s_j==s_i}  (== stable descending argsort position)
__global__ __launch_bounds__(256) void rank_kernel(
    const float* __restrict__ scores, int* __restrict__ part_of,
    int* __restrict__ cidx, int* __restrict__ counters)
{
  int b = blockIdx.x >> 4;
  int i = (blockIdx.x & 15)*256 + threadIdx.x;
  float si = scores[b*NN + i];
  __shared__ float ss[256];
  int rank = 0;
  for (int c0=0;c0<NN;c0+=256){
    ss[threadIdx.x] = scores[b*NN + c0 + threadIdx.x];
    __syncthreads();
    for (int j=0;j<256;j++){
      float sj = ss[j];
      int jj = c0+j;
      rank += (sj > si) || (sj == si && jj < i);
    }
    __syncthreads();
  }
  int p = rank >> 10;       // rank / S
  part_of[b*NN + i] = p;
  int slot = atomicAdd(&counters[b*PP + p], 1);
  cidx[(b*PP + p)*SS + slot] = i;
}

// K4: deterministic partition-mean scores
__global__ __launch_bounds__(256) void pscore_kernel(
    const float* __restrict__ scores, const int* __restrict__ part_of,
    float* __restrict__ pscores)
{
  int bp = blockIdx.x, b = bp>>2, p = bp&3;
  float acc=0.f;
  for (int i=threadIdx.x; i<NN; i+=256)
    if (part_of[b*NN+i]==p) acc += scores[b*NN+i];
  __shared__ float sbuf[4];
  float s = block_sum<4>(acc, sbuf);
  if (threadIdx.x==0) pscores[bp] = s * (1.0f/(float)SS);
}

__global__ __launch_bounds__(64) void pw_kernel(const float* __restrict__ pscores,
                                                float* __restrict__ pw)
{
  int b = threadIdx.x;
  if (b < BB){
    float mx=-1e30f;
    for(int p=0;p<PP;p++) mx=fmaxf(mx,pscores[b*PP+p]);
    float s=0.f,e[PP];
    for(int p=0;p<PP;p++){ e[p]=__expf(pscores[b*PP+p]-mx); s+=e[p]; }
    for(int p=0;p<PP;p++) pw[b*PP+p]=e[p]/s;
  }
}

// K6: compact tokens into (b,p)-group-major layout
__global__ __launch_bounds__(256) void gather_kernel(
    const float* __restrict__ tokens, const int* __restrict__ cidx,
    float* __restrict__ Xc)
{
  long slot = blockIdx.x;
  int b = (int)(slot >> 12);
  int i = cidx[slot];
  Xc[slot*DD + threadIdx.x] = tokens[((long)b*NN + i)*DD + threadIdx.x];
}

// K7: decoder K/V precompute: mn = LN(m; an[p,l]); k = mn@wk[p,l]; v = mn@wv[p,l]
__global__ __launch_bounds__(512) void kv_kernel(
    const float* __restrict__ m, const float* __restrict__ an_g,
    const float* __restrict__ an_b, const float* __restrict__ wk,
    const float* __restrict__ wv, float* __restrict__ kvk, float* __restrict__ kvv)
{
  int idx = blockIdx.x;              // (pl*B + b)*NT + j, grid = 256
  int j = idx & 7, b = (idx>>3)&3, pl = idx>>5;
  int tid = threadIdx.x;
  __shared__ float mn[256];
  __shared__ float sbuf[8];
  float v = (tid<256) ? m[(b*NT+j)*DD + tid] : 0.0f;
  float s = block_sum<8>(v, sbuf);
  float mu = s*(1.0f/256.0f);
  float dv = (tid<256)? v-mu : 0.0f;
  float q = block_sum<8>(dv*dv, sbuf);
  float rs = rsqrtf(q*(1.0f/256.0f)+1e-5f);
  if (tid<256) mn[tid] = dv*rs*an_g[pl*DD+tid] + an_b[pl*DD+tid];
  __syncthreads();
  float ka=0.f, va=0.f;
  for (int c=0;c<DD;c++){
    float mc = mn[c];
    ka = fmaf(mc, wk[((long)pl*DD + c)*INNER + tid], ka);
    va = fmaf(mc, wv[((long)pl*DD + c)*INNER + tid], va);
  }
  long off = ((long)pl*BB + b)*(NT*INNER) + j*INNER + tid;
  kvk[off]=ka; kvv[off]=va;
}

// K8: rowwise LN of compacted state (per-p gamma/beta, pre-offset by layer)
__global__ __launch_bounds__(256) void ln_rows_kernel(
    const float* __restrict__ X, float* __restrict__ Y,
    const float* __restrict__ gamma, const float* __restrict__ beta)
{
  long row = blockIdx.x;
  int p = (int)((row>>10)&3);
  int d = threadIdx.x;
  float v = X[row*DD+d];
  __shared__ float sbuf[4];
  float mu = block_sum<4>(v,sbuf)*(1.0f/256.0f);
  float dv = v-mu;
  float var = block_sum<4>(dv*dv,sbuf)*(1.0f/256.0f);
  Y[row*DD+d] = dv*rsqrtf(var+1e-5f)*gamma[p*(LL*DD)+d]+beta[p*(LL*DD)+d];
}

// K9: generic fp32 tiled GEMM, per-group z: C[z] (+)= [gelu](A[z] @ Bw[p(z)] + bias[p(z)])
template<bool HASBIAS, bool GELU, bool ACCUM>
__global__ __launch_bounds__(256) void gemm_kernel(
    const float* __restrict__ A, int lda, long astride,
    const float* __restrict__ Bw, int ldb, long bpstride,
    const float* __restrict__ bias, int bias_pstride,
    float* __restrict__ C, int ldc, long cstride,
    int M, int Nn, int K)
{
  int g = blockIdx.z;
  int p = g & 3;
  const float* Ag = A + (long)g*astride;
  const float* Bg = Bw + (long)p*bpstride;
  float* Cg = C + (long)g*cstride;
  const float* biasg = HASBIAS ? (bias + (long)p*bias_pstride) : nullptr;

  __shared__ float As[16][68];
  __shared__ float Bs[16][68];
  int tid = threadIdx.x;
  int row0 = blockIdx.y*64;
  int col0 = blockIdx.x*64;
  int tm = (tid>>4)<<2;
  int tn = (tid&15)<<2;
  float acc[4][4] = {};
  for (int k0=0;k0<K;k0+=16){
    #pragma unroll
    for (int i=0;i<4;i++){
      int l = tid + i*256;
      int r = l>>4, c = l&15;
      As[c][r] = Ag[(long)(row0+r)*lda + k0 + c];
    }
    #pragma unroll
    for (int i=0;i<4;i++){
      int l = tid + i*256;
      int r = l>>6, c = l&63;
      Bs[r][c] = Bg[(long)(k0+r)*ldb + col0 + c];
    }
    __syncthreads();
    #pragma unroll
    for (int kk=0;kk<16;kk++){
      float a[4],b[4];
      #pragma unroll
      for (int i=0;i<4;i++){ a[i]=As[kk][tm+i]; b[i]=Bs[kk][tn+i]; }
      #pragma unroll
      for (int i=0;i<4;i++)
        #pragma unroll
        for (int j=0;j<4;j++) acc[i][j] = fmaf(a[i], b[j], acc[i][j]);
    }
    __syncthreads();
  }
  #pragma unroll
  for (int i=0;i<4;i++){
    int r = row0+tm+i;
    #pragma unroll
    for (int j=0;j<4;j++){
      int cc = col0+tn+j;
      float v = acc[i][j];
      if (HASBIAS) v += biasg[cc];
      if (GELU) v = 0.5f*v*(1.0f+erff(v*0.70710678118654752440f));
      if (ACCUM) Cg[(long)r*ldc+cc] += v;
      else       Cg[(long)r*ldc+cc] = v;
    }
  }
}

// K10: 8-head / 8-slot decoder attention; in-place on Q buffer (1 wave per token)
__global__ __launch_bounds__(256) void attn_kernel(
    float* __restrict__ QO, const float* __restrict__ kvk,
    const float* __restrict__ kvv, int l)
{
  __shared__ float q_sm[4][8][68];
  int w = threadIdx.x>>6, lane = threadIdx.x&63;
  long tg = (long)blockIdx.x*4 + w;
  int g = (int)(tg>>10); int b = g>>2, p = g&3;
  long kvoff = (long)((p*LL+l)*BB + b)*(NT*INNER);
  const float* Q = QO + tg*INNER;
  #pragma unroll
  for (int i=0;i<8;i++) q_sm[w][i][lane] = Q[i*64+lane];
  __syncthreads();
  int h = lane>>3, j = lane&7;
  const float* kp = kvk + kvoff + j*INNER + h*64;
  float acc=0.f;
  #pragma unroll
  for (int dh=0;dh<64;dh++) acc = fmaf(q_sm[w][h][dh], kp[dh], acc);
  acc *= SCALE;
  float mx = acc;
  mx = fmaxf(mx, __shfl_xor(mx,1));
  mx = fmaxf(mx, __shfl_xor(mx,2));
  mx = fmaxf(mx, __shfl_xor(mx,4));
  float e = __expf(acc-mx);
  float s = e;
  s += __shfl_xor(s,1); s += __shfl_xor(s,2); s += __shfl_xor(s,4);
  float a = e/s;
  float o[8] = {0,0,0,0,0,0,0,0};
  #pragma unroll
  for (int jj=0;jj<8;jj++){
    float aj = __shfl(a, (lane&56)+jj);
    const float* vp = kvv + kvoff + jj*INNER + lane*8;
    #pragma unroll
    for (int qi=0;qi<8;qi++) o[qi] = fmaf(aj, vp[qi], o[qi]);
  }
  float* Op = QO + tg*INNER + lane*8;
  #pragma unroll
  for (int qi=0;qi<8;qi++) Op[qi] = o[qi];
}

// K11: scale by pw, final LN, scatter to original token order
__global__ __launch_bounds__(256) void final_kernel(
    const float* __restrict__ Xc, const int* __restrict__ cidx,
    const float* __restrict__ pw, const float* __restrict__ fln_g,
    const float* __restrict__ fln_b, float* __restrict__ out)
{
  long slot = blockIdx.x;
  int b = (int)(slot>>12);
  int p = (int)((slot>>10)&3);
  int i = cidx[slot];
  int d = threadIdx.x;
  float v = Xc[slot*DD+d] * pw[b*PP+p];
  __shared__ float sbuf[4];
  float mu = block_sum<4>(v, sbuf)*(1.0f/256.0f);
  float dv = v-mu;
  float var = block_sum<4>(dv*dv, sbuf)*(1.0f/256.0f);
  out[((long)b*NN+i)*DD + d] = dv*rsqrtf(var+1e-5f)*fln_g[d]+fln_b[d];
}

extern "C" void kernel_launch(void* const* d_in, const int* in_sizes, int n_in,
                              void* d_out, int out_size, void* d_ws, size_t ws_size,
                              hipStream_t stream)
{
  (void)in_sizes; (void)n_in; (void)out_size; (void)ws_size;
  const float* x     =(const float*)d_in[0];
  const float* m     =(const float*)d_in[1];
  const float* proj_w=(const float*)d_in[2];
  const float* proj_b=(const float*)d_in[3];
  const float* lnp_g =(const float*)d_in[4];
  const float* lnp_b =(const float*)d_in[5];
  const float* sq_w  =(const float*)d_in[6];
  const float* sq_b  =(const float*)d_in[7];
  const float* sk_w  =(const float*)d_in[8];
  const float* sk_b  =(const float*)d_in[9];
  const float* sv_w  =(const float*)d_in[10];
  const float* sv_b  =(const float*)d_in[11];
  const float* an_g  =(const float*)d_in[12];
  const float* an_b  =(const float*)d_in[13];
  const float* wq    =(const float*)d_in[14];
  const float* wk    =(const float*)d_in[15];
  const float* wv    =(const float*)d_in[16];
  const float* wo    =(const float*)d_in[17];
  const float* wo_b  =(const float*)d_in[18];
  const float* fn_g  =(const float*)d_in[19];
  const float* fn_b  =(const float*)d_in[20];
  const float* w1    =(const float*)d_in[21];
  const float* b1    =(const float*)d_in[22];
  const float* w2    =(const float*)d_in[23];
  const float* b2    =(const float*)d_in[24];
  const float* fln_g =(const float*)d_in[25];
  const float* fln_b =(const float*)d_in[26];
  float* out = (float*)d_out;

  float* ws = (float*)d_ws;
  float* tokens = ws;  ws += 4194304;           // B*N*D
  float* Xc     = ws;  ws += 4194304;           // compacted state
  float* tmp1   = ws;  ws += 4194304;           // LN output
  float* tmp2   = ws;  ws += 8388608;           // Q / attn-out / F1-half
  float* kvk    = ws;  ws += 131072;            // P*L*B*NT*INNER
  float* kvv    = ws;  ws += 131072;
  float* ksc    = ws;  ws += 8192;              // B*NT*D
  float* vsc    = ws;  ws += 64;
  float* scores = ws;  ws += 16384;
  float* pscores= ws;  ws += 16;
  float* pw     = ws;  ws += 16;
  int* cidx     = (int*)ws;  ws += 16384;
  int* part_of  = (int*)ws;  ws += 16384;
  int* counters = (int*)ws;  ws += 64;

  hipMemsetAsync(counters, 0, BB*PP*sizeof(int), stream);
  proj_ln_kernel<<<1024,256,0,stream>>>(x, proj_w, proj_b, lnp_g, lnp_b, tokens);
  scorer_kv_kernel<<<32,256,0,stream>>>(m, sk_w, sk_b, sv_w, sv_b, ksc, vsc);
  scores_kernel<<<1024,256,0,stream>>>(tokens, sq_w, sq_b, ksc, vsc, scores);
  rank_kernel<<<64,256,0,stream>>>(scores, part_of, cidx, counters);
  pscore_kernel<<<16,256,0,stream>>>(scores, part_of, pscores);
  pw_kernel<<<1,64,0,stream>>>(pscores, pw);
  gather_kernel<<<16384,256,0,stream>>>(tokens, cidx, Xc);
  kv_kernel<<<256,512,0,stream>>>(m, an_g, an_b, wk, wv, kvk, kvv);

  for (int l=0;l<LL;l++){
    // xn = LN(Xc; an[p,l])
    ln_rows_kernel<<<16384,256,0,stream>>>(Xc, tmp1, an_g + l*DD, an_b + l*DD);
    // Q = xn @ wq[p,l]   (1024x256 @ 256x512 per group)
    gemm_kernel<false,false,false><<<dim3(8,16,16),256,0,stream>>>(
        tmp1,DD,(long)SS*DD, wq + (long)l*DD*INNER,INNER,(long)LL*DD*INNER,
        nullptr,0, tmp2,INNER,(long)SS*INNER, SS,INNER,DD);
    // attention over 8 memory slots (in-place on tmp2)
    attn_kernel<<<4096,256,0,stream>>>(tmp2, kvk, kvv, l);
    // Xc += AO @ wo[p,l] + wo_b[p,l]
    gemm_kernel<true,false,true><<<dim3(4,16,16),256,0,stream>>>(
        tmp2,INNER,(long)SS*INNER, wo + (long)l*INNER*DD,DD,(long)LL*INNER*DD,
        wo_b + l*DD, LL*DD, Xc,DD,(long)SS*DD, SS,DD,INNER);
    // h = LN(Xc; fn[p,l])
    ln_rows_kernel<<<16384,256,0,stream>>>(Xc, tmp1, fn_g + l*DD, fn_b + l*DD);
    // FF in two 512-wide halves to bound workspace
    for (int h=0;h<2;h++){
      gemm_kernel<true,true,false><<<dim3(8,16,16),256,0,stream>>>(
          tmp1,DD,(long)SS*DD, w1 + (long)l*DD*FFD + h*512,FFD,(long)LL*DD*FFD,
          b1 + l*FFD + h*512, LL*FFD, tmp2,512,(long)SS*512, SS,512,DD);
      if (h==0)
        gemm_kernel<true,false,true><<<dim3(4,16,16),256,0,stream>>>(
            tmp2,512,(long)SS*512, w2 + (long)l*FFD*DD + (long)h*512*DD,DD,(long)LL*FFD*DD,
            b2 + l*DD, LL*DD, Xc,DD,(long)SS*DD, SS,DD,512);
      else
        gemm_kernel<false,false,true><<<dim3(4,16,16),256,0,stream>>>(
            tmp2,512,(long)SS*512, w2 + (long)l*FFD*DD + (long)h*512*DD,DD,(long)LL*FFD*DD,
            nullptr,0, Xc,DD,(long)SS*DD, SS,DD,512);
    }
  }
  final_kernel<<<16384,256,0,stream>>>(Xc, cidx, pw, fln_g, fln_b, out);
}

// Round 2
// 537.987 us; speedup vs baseline: 2.5609x; 2.5609x over previous
//
#include <hip/hip_runtime.h>
#include <hip/hip_bf16.h>
#include <math.h>

// Problem constants
#define BB 4
#define CC 128
#define NN 4096      // H*W
#define DD 256
#define INNER 512
#define FFD 1024
#define PP 4
#define LL 2
#define NT 8
#define SS 1024      // NN/PP
#define SCALE 0.0625f // 1/sqrt(256)

typedef __attribute__((ext_vector_type(8))) short bf16x8;
typedef __attribute__((ext_vector_type(4))) float f32x4;

#define GLD_LDS16(g, l) __builtin_amdgcn_global_load_lds( \
    (const __attribute__((address_space(1))) void*)(g), \
    (__attribute__((address_space(3))) void*)(l), 16, 0, 0)

template<int NW>
__device__ inline float block_sum(float v, float* sbuf){
  #pragma unroll
  for (int mk=32; mk; mk>>=1) v += __shfl_xor(v, mk);
  int w = threadIdx.x>>6;
  if ((threadIdx.x&63)==0) sbuf[w]=v;
  __syncthreads();
  float r = 0.f;
  #pragma unroll
  for (int k=0;k<NW;k++) r += sbuf[k];
  __syncthreads();
  return r;
}

// K1: tokens = LN(x(1x1conv)proj_w + proj_b).  16 tokens per 256-thread block.
__global__ __launch_bounds__(256) void proj_ln_kernel(
    const float* __restrict__ x, const float* __restrict__ proj_w,
    const float* __restrict__ proj_b, const float* __restrict__ lnp_g,
    const float* __restrict__ lnp_b, float* __restrict__ tokens)
{
  int b  = blockIdx.x >> 8;          // 256 blocks per batch
  int n0 = (blockIdx.x & 255) * 16;
  int tid = threadIdx.x;
  __shared__ float xs[16][132];
  __shared__ float ys[16][260];
  __shared__ float mu_s[16], rs_s[16];
  #pragma unroll
  for (int i=0;i<8;i++){
    int l = tid + i*256;
    int t = l & 15, c = l >> 4;
    xs[t][c] = x[(long)(b*CC + c)*NN + n0 + t];
  }
  __syncthreads();
  float acc[16];
  #pragma unroll
  for (int t=0;t<16;t++) acc[t]=0.f;
  for (int c=0;c<CC;c++){
    float wv = proj_w[c*DD + tid];
    #pragma unroll
    for (int t=0;t<16;t++) acc[t] = fmaf(xs[t][c], wv, acc[t]);
  }
  float pb = proj_b[tid];
  #pragma unroll
  for (int t=0;t<16;t++) ys[t][tid] = acc[t] + pb;
  __syncthreads();
  int w = tid>>6, lane = tid&63;
  for (int k=0;k<4;k++){
    int t = w*4+k;
    float s = ys[t][lane] + ys[t][lane+64] + ys[t][lane+128] + ys[t][lane+192];
    #pragma unroll
    for (int mk=32; mk; mk>>=1) s += __shfl_xor(s, mk);
    float mu = s*(1.0f/256.0f);
    float d0=ys[t][lane]-mu, d1=ys[t][lane+64]-mu, d2=ys[t][lane+128]-mu, d3=ys[t][lane+192]-mu;
    float q = d0*d0+d1*d1+d2*d2+d3*d3;
    #pragma unroll
    for (int mk=32; mk; mk>>=1) q += __shfl_xor(q, mk);
    if (lane==0){ mu_s[t]=mu; rs_s[t]=rsqrtf(q*(1.0f/256.0f)+1e-5f); }
  }
  __syncthreads();
  float g = lnp_g[tid], be = lnp_b[tid];
  #pragma unroll
  for (int t=0;t<16;t++){
    tokens[((long)(b*NN + n0 + t))*DD + tid] = (ys[t][tid]-mu_s[t])*rs_s[t]*g + be;
  }
}

// K2a: scorer k = m@sk_w + sk_b  (B,NT,D);  v = m@sv_w + sv_b (B,NT)
__global__ __launch_bounds__(256) void scorer_kv_kernel(
    const float* __restrict__ m, const float* __restrict__ sk_w,
    const float* __restrict__ sk_b, const float* __restrict__ sv_w,
    const float* __restrict__ sv_b, float* __restrict__ ksc, float* __restrict__ vsc)
{
  int bj = blockIdx.x;               // B*NT = 32
  int d = threadIdx.x;
  __shared__ float ms[256];
  __shared__ float sbuf[4];
  ms[d] = m[bj*DD + d];
  __syncthreads();
  float acc=0.f;
  for(int c=0;c<DD;c++) acc = fmaf(ms[c], sk_w[c*DD + d], acc);
  ksc[bj*DD + d] = acc + sk_b[d];
  float sv = block_sum<4>(ms[d]*sv_w[d], sbuf);
  if(d==0) vsc[bj] = sv + sv_b[0];
}

// K2b: per-token score via tiny cross-attn (softmax over 8 memory slots)
__global__ __launch_bounds__(256) void scores_kernel(
    const float* __restrict__ tokens, const float* __restrict__ sq_w,
    const float* __restrict__ sq_b, const float* __restrict__ ksc,
    const float* __restrict__ vsc, float* __restrict__ scores)
{
  int b  = blockIdx.x >> 8;
  int t0 = (blockIdx.x & 255) * 16;
  int tid = threadIdx.x;
  __shared__ float ts[16][260];
  __shared__ float lg[16][8];
  for (int t=0;t<16;t++) ts[t][tid] = tokens[((long)(b*NN + t0 + t))*DD + tid];
  __syncthreads();
  float qa[16];
  #pragma unroll
  for(int t=0;t<16;t++) qa[t]=0.f;
  for(int c=0;c<DD;c++){
    float w = sq_w[c*DD + tid];
    #pragma unroll
    for(int t=0;t<16;t++) qa[t] = fmaf(ts[t][c], w, qa[t]);
  }
  __syncthreads();
  float qb = sq_b[tid];
  for(int t=0;t<16;t++) ts[t][tid] = qa[t] + qb;
  __syncthreads();
  if (tid < 128){
    int t = tid>>3, j = tid&7;
    const float* kk = ksc + (b*NT + j)*DD;
    float acc=0.f;
    for(int c=0;c<DD;c++) acc = fmaf(ts[t][c], kk[c], acc);
    lg[t][j] = acc * SCALE;
  }
  __syncthreads();
  if (tid < 16){
    float mx=-1e30f;
    for(int j=0;j<NT;j++) mx=fmaxf(mx,lg[tid][j]);
    float s=0.f, sc=0.f;
    for(int j=0;j<NT;j++){ float e=__expf(lg[tid][j]-mx); s+=e; sc+=e*vsc[b*NT+j]; }
    scores[b*NN + t0 + tid] = sc/s;
  }
}

// K3a: partial ranks: 1024 blocks = (b, itile, jtile); atomicAdd per token
__global__ __launch_bounds__(256) void rank_partial_kernel(
    const float* __restrict__ scores, int* __restrict__ rank)
{
  int b  = blockIdx.x >> 8;
  int it = (blockIdx.x >> 4) & 15;
  int jt = blockIdx.x & 15;
  int i = it*256 + threadIdx.x;
  float si = scores[b*NN + i];
  __shared__ float ss[256];
  ss[threadIdx.x] = scores[b*NN + jt*256 + threadIdx.x];
  __syncthreads();
  int jbase = jt*256;
  int cnt = 0;
  #pragma unroll 4
  for (int j=0;j<256;j++){
    float sj = ss[j];
    cnt += (sj > si) || (sj == si && (jbase+j) < i);
  }
  atomicAdd(&rank[b*NN+i], cnt);
}

// K3b: rank is a permutation -> slot = rank & (SS-1), no atomics needed
__global__ __launch_bounds__(256) void rank_finalize_kernel(
    const int* __restrict__ rank, int* __restrict__ cidx)
{
  int b = blockIdx.x >> 4;
  int i = (blockIdx.x & 15)*256 + threadIdx.x;
  int rk = rank[b*NN + i];
  int p = rk >> 10;
  cidx[(b*PP + p)*SS + (rk & (SS-1))] = i;
}

// K4: deterministic partition-mean scores (via cidx)
__global__ __launch_bounds__(256) void pscore_kernel(
    const float* __restrict__ scores, const int* __restrict__ cidx,
    float* __restrict__ pscores)
{
  int bp = blockIdx.x, b = bp>>2;
  float acc=0.f;
  for (int s=threadIdx.x; s<SS; s+=256) acc += scores[b*NN + cidx[bp*SS+s]];
  __shared__ float sbuf[4];
  float s = block_sum<4>(acc, sbuf);
  if (threadIdx.x==0) pscores[bp] = s * (1.0f/(float)SS);
}

__global__ __launch_bounds__(64) void pw_kernel(const float* __restrict__ pscores,
                                                float* __restrict__ pw)
{
  int b = threadIdx.x;
  if (b < BB){
    float mx=-1e30f;
    for(int p=0;p<PP;p++) mx=fmaxf(mx,pscores[b*PP+p]);
    float s=0.f,e[PP];
    for(int p=0;p<PP;p++){ e[p]=__expf(pscores[b*PP+p]-mx); s+=e[p]; }
    for(int p=0;p<PP;p++) pw[b*PP+p]=e[p]/s;
  }
}

// K6: compact tokens into (b,p)-group-major layout
__global__ __launch_bounds__(256) void gather_kernel(
    const float* __restrict__ tokens, const int* __restrict__ cidx,
    float* __restrict__ Xc)
{
  long slot = blockIdx.x;
  int b = (int)(slot >> 12);
  int i = cidx[slot];
  Xc[slot*DD + threadIdx.x] = tokens[((long)b*NN + i)*DD + threadIdx.x];
}

// K7: decoder K/V precompute: mn = LN(m; an[p,l]); k = mn@wk[p,l]; v = mn@wv[p,l]
__global__ __launch_bounds__(512) void kv_kernel(
    const float* __restrict__ m, const float* __restrict__ an_g,
    const float* __restrict__ an_b, const float* __restrict__ wk,
    const float* __restrict__ wv, float* __restrict__ kvk, float* __restrict__ kvv)
{
  int idx = blockIdx.x;              // (pl*B + b)*NT + j, grid = 256
  int j = idx & 7, b = (idx>>3)&3, pl = idx>>5;
  int tid = threadIdx.x;
  __shared__ float mn[256];
  __shared__ float sbuf[8];
  float v = (tid<256) ? m[(b*NT+j)*DD + tid] : 0.0f;
  float s = block_sum<8>(v, sbuf);
  float mu = s*(1.0f/256.0f);
  float dv = (tid<256)? v-mu : 0.0f;
  float q = block_sum<8>(dv*dv, sbuf);
  float rs = rsqrtf(q*(1.0f/256.0f)+1e-5f);
  if (tid<256) mn[tid] = dv*rs*an_g[pl*DD+tid] + an_b[pl*DD+tid];
  __syncthreads();
  float ka=0.f, va=0.f;
  for (int c=0;c<DD;c++){
    float mc = mn[c];
    ka = fmaf(mc, wk[((long)pl*DD + c)*INNER + tid], ka);
    va = fmaf(mc, wv[((long)pl*DD + c)*INNER + tid], va);
  }
  long off = ((long)pl*BB + b)*(NT*INNER) + j*INNER + tid;
  kvk[off]=ka; kvv[off]=va;
}

// K8: rowwise LN of compacted state -> bf16 (per-p gamma/beta, pre-offset by layer)
__global__ __launch_bounds__(256) void ln_rows_kernel(
    const float* __restrict__ X, __hip_bfloat16* __restrict__ Y,
    const float* __restrict__ gamma, const float* __restrict__ beta)
{
  long row = blockIdx.x;
  int p = (int)((row>>10)&3);
  int d = threadIdx.x;
  float v = X[row*DD+d];
  __shared__ float sbuf[4];
  float mu = block_sum<4>(v,sbuf)*(1.0f/256.0f);
  float dv = v-mu;
  float var = block_sum<4>(dv*dv,sbuf)*(1.0f/256.0f);
  Y[row*DD+d] = __float2bfloat16(dv*rsqrtf(var+1e-5f)*gamma[p*(LL*DD)+d]+beta[p*(LL*DD)+d]);
}

// Kw: weight convert fp32 [PL][K][N] -> bf16 transposed [PL][N][K]
__global__ __launch_bounds__(256) void wconv_kernel(
    const float* __restrict__ w, __hip_bfloat16* __restrict__ wT, int K, int N)
{
  int pl = blockIdx.z;
  int n0 = blockIdx.x*64, k0 = blockIdx.y*64;
  __shared__ float t[64][65];
  int tid = threadIdx.x;
  #pragma unroll
  for (int i=0;i<16;i++){
    int idx = i*256+tid;
    int kk = idx>>6, nn = idx&63;
    t[kk][nn] = w[((long)pl*K + k0+kk)*N + n0+nn];
  }
  __syncthreads();
  #pragma unroll
  for (int i=0;i<16;i++){
    int idx = i*256+tid;
    int nn = idx>>6, kk = idx&63;
    wT[((long)pl*N + n0+nn)*K + k0+kk] = __float2bfloat16(t[kk][nn]);
  }
}

// K9: MFMA bf16 GEMM. C[g] (+)= [gelu](A[g] @ BT[p(g)]^T + bias[p(g)])
// A: [g][M=1024][K] bf16 row-major; BT: [p][N][K] bf16 (i.e. B transposed)
// tile 128x128, BK=64, 4 waves (2x2), 64x64 per wave, 16x16x32 mfma
// LDS: linear dest for global_load_lds; XOR swizzle (slot ^= row&7) applied on
// the global SOURCE address and on the ds_read side (T21 both-sides rule).
template<bool HASBIAS, bool GELU, bool ACCUM>
__global__ __launch_bounds__(256) void mfma_gemm(
    const __hip_bfloat16* __restrict__ A, long astride, int K,
    const __hip_bfloat16* __restrict__ BT, long bpstride,
    const float* __restrict__ bias, int bias_pstride,
    void* __restrict__ Cp, int ldc, long cstride)
{
  int g = blockIdx.z;
  int p = g & 3;
  const __hip_bfloat16* Ag = A  + (long)g*astride + (long)blockIdx.y*128*K;
  const __hip_bfloat16* Bg = BT + (long)p*bpstride + (long)blockIdx.x*128*K;
  const float* biasg = HASBIAS ? (bias + (long)p*bias_pstride) : nullptr;

  __shared__ __align__(16) __hip_bfloat16 Asm[128*64];
  __shared__ __align__(16) __hip_bfloat16 Bsm[128*64];

  int tid = threadIdx.x;
  int w = tid>>6, lane = tid&63;
  int wr = w>>1, wc = w&1;
  int lr = lane>>4, lc = lane&15;

  f32x4 acc[4][4] = {};

  for (int k0=0; k0<K; k0+=64){
    // stage A and B tiles: 1024 segs of 16B each per operand, 4 per thread
    #pragma unroll
    for (int i=0;i<4;i++){
      int seg = i*256 + tid;
      int r = seg>>3, sl = seg&7;
      int sg = sl ^ (r&7);                       // pre-swizzled source slot
      GLD_LDS16(Ag + (long)r*K + k0 + sg*8, Asm + (long)(i*256 + (tid & ~63))*8);
    }
    #pragma unroll
    for (int i=0;i<4;i++){
      int seg = i*256 + tid;
      int r = seg>>3, sl = seg&7;
      int sg = sl ^ (r&7);
      GLD_LDS16(Bg + (long)r*K + k0 + sg*8, Bsm + (long)(i*256 + (tid & ~63))*8);
    }
    asm volatile("s_waitcnt vmcnt(0)" ::: "memory");
    __syncthreads();

    #pragma unroll
    for (int kc=0;kc<2;kc++){
      bf16x8 af[4], bfr[4];
      #pragma unroll
      for (int mi=0;mi<4;mi++){
        int r = wr*64 + mi*16 + lc;
        int s = kc*4 + lr;
        af[mi] = *(const bf16x8*)(Asm + r*64 + (s ^ (r&7))*8);
      }
      #pragma unroll
      for (int ni=0;ni<4;ni++){
        int r = wc*64 + ni*16 + lc;
        int s = kc*4 + lr;
        bfr[ni] = *(const bf16x8*)(Bsm + r*64 + (s ^ (r&7))*8);
      }
      #pragma unroll
      for (int mi=0;mi<4;mi++)
        #pragma unroll
        for (int ni=0;ni<4;ni++)
          acc[mi][ni] = __builtin_amdgcn_mfma_f32_16x16x32_bf16(af[mi], bfr[ni], acc[mi][ni], 0, 0, 0);
    }
    __syncthreads();
  }

  // epilogue: C row = by*128 + wr*64 + mi*16 + lr*4 + j ; col = bx*128 + wc*64 + ni*16 + lc
  if (ACCUM){
    float* Cg = (float*)Cp + (long)g*cstride;
    #pragma unroll
    for (int ni=0;ni<4;ni++){
      int col = blockIdx.x*128 + wc*64 + ni*16 + lc;
      float bv = HASBIAS ? biasg[col] : 0.0f;
      #pragma unroll
      for (int mi=0;mi<4;mi++){
        int row = blockIdx.y*128 + wr*64 + mi*16 + lr*4;
        #pragma unroll
        for (int j=0;j<4;j++){
          float v = acc[mi][ni][j] + bv;
          if (GELU) v = 0.5f*v*(1.0f+erff(v*0.70710678118654752440f));
          Cg[(long)(row+j)*ldc + col] += v;
        }
      }
    }
  } else {
    __hip_bfloat16* Cg = (__hip_bfloat16*)Cp + (long)g*cstride;
    #pragma unroll
    for (int ni=0;ni<4;ni++){
      int col = blockIdx.x*128 + wc*64 + ni*16 + lc;
      float bv = HASBIAS ? biasg[col] : 0.0f;
      #pragma unroll
      for (int mi=0;mi<4;mi++){
        int row = blockIdx.y*128 + wr*64 + mi*16 + lr*4;
        #pragma unroll
        for (int j=0;j<4;j++){
          float v = acc[mi][ni][j] + bv;
          if (GELU) v = 0.5f*v*(1.0f+erff(v*0.70710678118654752440f));
          Cg[(long)(row+j)*ldc + col] = __float2bfloat16(v);
        }
      }
    }
  }
}

// K10: 8-head / 8-slot decoder attention; in-place on bf16 Q buffer (1 wave per token)
__global__ __launch_bounds__(256) void attn_kernel(
    __hip_bfloat16* __restrict__ QO, const float* __restrict__ kvk,
    const float* __restrict__ kvv, int l)
{
  __shared__ float q_sm[4][8][68];
  int w = threadIdx.x>>6, lane = threadIdx.x&63;
  long tg = (long)blockIdx.x*4 + w;
  int g = (int)(tg>>10); int b = g>>2, p = g&3;
  long kvoff = (long)((p*LL+l)*BB + b)*(NT*INNER);
  const __hip_bfloat16* Q = QO + tg*INNER;
  #pragma unroll
  for (int i=0;i<8;i++) q_sm[w][i][lane] = __bfloat162float(Q[i*64+lane]);
  __syncthreads();
  int h = lane>>3, j = lane&7;
  const float* kp = kvk + kvoff + j*INNER + h*64;
  float acc=0.f;
  #pragma unroll
  for (int dh=0;dh<64;dh++) acc = fmaf(q_sm[w][h][dh], kp[dh], acc);
  acc *= SCALE;
  float mx = acc;
  mx = fmaxf(mx, __shfl_xor(mx,1));
  mx = fmaxf(mx, __shfl_xor(mx,2));
  mx = fmaxf(mx, __shfl_xor(mx,4));
  float e = __expf(acc-mx);
  float s = e;
  s += __shfl_xor(s,1); s += __shfl_xor(s,2); s += __shfl_xor(s,4);
  float a = e/s;
  float o[8] = {0,0,0,0,0,0,0,0};
  #pragma unroll
  for (int jj=0;jj<8;jj++){
    float aj = __shfl(a, (lane&56)+jj);
    const float* vp = kvv + kvoff + jj*INNER + lane*8;
    #pragma unroll
    for (int qi=0;qi<8;qi++) o[qi] = fmaf(aj, vp[qi], o[qi]);
  }
  __hip_bfloat16* Op = QO + tg*INNER + lane*8;
  #pragma unroll
  for (int qi=0;qi<8;qi++) Op[qi] = __float2bfloat16(o[qi]);
}

// K11: scale by pw, final LN, scatter to original token order
__global__ __launch_bounds__(256) void final_kernel(
    const float* __restrict__ Xc, const int* __restrict__ cidx,
    const float* __restrict__ pw, const float* __restrict__ fln_g,
    const float* __restrict__ fln_b, float* __restrict__ out)
{
  long slot = blockIdx.x;
  int b = (int)(slot>>12);
  int p = (int)((slot>>10)&3);
  int i = cidx[slot];
  int d = threadIdx.x;
  float v = Xc[slot*DD+d] * pw[b*PP+p];
  __shared__ float sbuf[4];
  float mu = block_sum<4>(v, sbuf)*(1.0f/256.0f);
  float dv = v-mu;
  float var = block_sum<4>(dv*dv, sbuf)*(1.0f/256.0f);
  out[((long)b*NN+i)*DD + d] = dv*rsqrtf(var+1e-5f)*fln_g[d]+fln_b[d];
}

extern "C" void kernel_launch(void* const* d_in, const int* in_sizes, int n_in,
                              void* d_out, int out_size, void* d_ws, size_t ws_size,
                              hipStream_t stream)
{
  (void)in_sizes; (void)n_in; (void)out_size; (void)ws_size;
  const float* x     =(const float*)d_in[0];
  const float* m     =(const float*)d_in[1];
  const float* proj_w=(const float*)d_in[2];
  const float* proj_b=(const float*)d_in[3];
  const float* lnp_g =(const float*)d_in[4];
  const float* lnp_b =(const float*)d_in[5];
  const float* sq_w  =(const float*)d_in[6];
  const float* sq_b  =(const float*)d_in[7];
  const float* sk_w  =(const float*)d_in[8];
  const float* sk_b  =(const float*)d_in[9];
  const float* sv_w  =(const float*)d_in[10];
  const float* sv_b  =(const float*)d_in[11];
  const float* an_g  =(const float*)d_in[12];
  const float* an_b  =(const float*)d_in[13];
  const float* wq    =(const float*)d_in[14];
  const float* wk    =(const float*)d_in[15];
  const float* wv    =(const float*)d_in[16];
  const float* wo    =(const float*)d_in[17];
  const float* wo_b  =(const float*)d_in[18];
  const float* fn_g  =(const float*)d_in[19];
  const float* fn_b  =(const float*)d_in[20];
  const float* w1    =(const float*)d_in[21];
  const float* b1    =(const float*)d_in[22];
  const float* w2    =(const float*)d_in[23];
  const float* b2    =(const float*)d_in[24];
  const float* fln_g =(const float*)d_in[25];
  const float* fln_b =(const float*)d_in[26];
  float* out = (float*)d_out;

  float* ws = (float*)d_ws;
  float* tokens = ws;  ws += 4194304;   // 16 MB; also first half of actF alias
  float* actQf  = ws;  ws += 4194304;   // 16 MB; actQ bf16 (16384x512); 2nd half of actF
  float* Xc     = ws;  ws += 4194304;   // 16 MB fp32 residual
  float* actAf  = ws;  ws += 2097152;   // 8 MB; actA bf16 (16384x256)
  float* wqTf   = ws;  ws += 524288;    // [P][L][512][256] bf16
  float* woTf   = ws;  ws += 524288;    // [P][L][256][512] bf16
  float* w1Tf   = ws;  ws += 1048576;   // [P][L][1024][256] bf16
  float* w2Tf   = ws;  ws += 1048576;   // [P][L][256][1024] bf16
  float* kvk    = ws;  ws += 131072;    // P*L*B*NT*INNER fp32
  float* kvv    = ws;  ws += 131072;
  float* ksc    = ws;  ws += 8192;      // B*NT*D
  float* vsc    = ws;  ws += 64;
  float* scores = ws;  ws += 16384;
  float* pscores= ws;  ws += 16;
  float* pw     = ws;  ws += 16;
  int* rank     = (int*)ws;  ws += 16384;
  int* cidx     = (int*)ws;  ws += 16384;

  __hip_bfloat16* actA = (__hip_bfloat16*)actAf;
  __hip_bfloat16* actQ = (__hip_bfloat16*)actQf;
  __hip_bfloat16* actF = (__hip_bfloat16*)tokens;  // aliases tokens+actQ (both dead by FF1)
  __hip_bfloat16* wqT  = (__hip_bfloat16*)wqTf;
  __hip_bfloat16* woT  = (__hip_bfloat16*)woTf;
  __hip_bfloat16* w1T  = (__hip_bfloat16*)w1Tf;
  __hip_bfloat16* w2T  = (__hip_bfloat16*)w2Tf;

  hipMemsetAsync(rank, 0, BB*NN*sizeof(int), stream);

  proj_ln_kernel<<<1024,256,0,stream>>>(x, proj_w, proj_b, lnp_g, lnp_b, tokens);
  scorer_kv_kernel<<<32,256,0,stream>>>(m, sk_w, sk_b, sv_w, sv_b, ksc, vsc);
  scores_kernel<<<1024,256,0,stream>>>(tokens, sq_w, sq_b, ksc, vsc, scores);
  rank_partial_kernel<<<1024,256,0,stream>>>(scores, rank);
  rank_finalize_kernel<<<64,256,0,stream>>>(rank, cidx);
  pscore_kernel<<<16,256,0,stream>>>(scores, cidx, pscores);
  pw_kernel<<<1,64,0,stream>>>(pscores, pw);
  gather_kernel<<<16384,256,0,stream>>>(tokens, cidx, Xc);
  kv_kernel<<<256,512,0,stream>>>(m, an_g, an_b, wk, wv, kvk, kvv);

  // weight convert+transpose to bf16 [P][L][N][K]
  wconv_kernel<<<dim3(8,4,8),256,0,stream>>>(wq, wqT, DD, INNER);
  wconv_kernel<<<dim3(4,8,8),256,0,stream>>>(wo, woT, INNER, DD);
  wconv_kernel<<<dim3(16,4,8),256,0,stream>>>(w1, w1T, DD, FFD);
  wconv_kernel<<<dim3(4,16,8),256,0,stream>>>(w2, w2T, FFD, DD);

  for (int l=0;l<LL;l++){
    // xn = LN(Xc; an[p,l]) -> bf16
    ln_rows_kernel<<<16384,256,0,stream>>>(Xc, actA, an_g + l*DD, an_b + l*DD);
    // Q = xn @ wq[p,l]  (1024x256x512 per group) -> bf16
    mfma_gemm<false,false,false><<<dim3(4,8,16),256,0,stream>>>(
        actA, (long)SS*DD, DD, wqT + (long)l*INNER*DD, (long)LL*INNER*DD,
        nullptr, 0, actQ, INNER, (long)SS*INNER);
    // attention over 8 memory slots (in-place on actQ)
    attn_kernel<<<4096,256,0,stream>>>(actQ, kvk, kvv, l);
    // Xc += AO @ wo[p,l] + wo_b[p,l]   (1024x512x256)
    mfma_gemm<true,false,true><<<dim3(2,8,16),256,0,stream>>>(
        actQ, (long)SS*INNER, INNER, woT + (long)l*DD*INNER, (long)LL*DD*INNER,
        wo_b + l*DD, LL*DD, Xc, DD, (long)SS*DD);
    // h = LN(Xc; fn[p,l]) -> bf16
    ln_rows_kernel<<<16384,256,0,stream>>>(Xc, actA, fn_g + l*DD, fn_b + l*DD);
    // F = gelu(h @ w1[p,l] + b1[p,l]) (1024x256x1024) -> bf16
    mfma_gemm<true,true,false><<<dim3(8,8,16),256,0,stream>>>(
        actA, (long)SS*DD, DD, w1T + (long)l*FFD*DD, (long)LL*FFD*DD,
        b1 + l*FFD, LL*FFD, actF, FFD, (long)SS*FFD);
    // Xc += F @ w2[p,l] + b2[p,l]   (1024x1024x256)
    mfma_gemm<true,false,true><<<dim3(2,8,16),256,0,stream>>>(
        actF, (long)SS*FFD, FFD, w2T + (long)l*DD*FFD, (long)LL*DD*FFD,
        b2 + l*DD, LL*DD, Xc, DD, (long)SS*DD);
  }
  final_kernel<<<16384,256,0,stream>>>(Xc, cidx, pw, fln_g, fln_b, out);
}

// Round 5
// 417.688 us; speedup vs baseline: 3.2985x; 1.2880x over previous
//
#include <hip/hip_runtime.h>
#include <hip/hip_bf16.h>
#include <math.h>

// Problem constants
#define BB 4
#define CC 128
#define NN 4096      // H*W
#define DD 256
#define INNER 512
#define FFD 1024
#define PP 4
#define LL 2
#define NT 8
#define SS 1024      // NN/PP
#define SCALE 0.0625f // 1/sqrt(256)

typedef __attribute__((ext_vector_type(8))) short bf16x8;
typedef __attribute__((ext_vector_type(8))) short short8;
typedef __attribute__((ext_vector_type(4))) float f32x4;

#define GLD_LDS16(g, l) __builtin_amdgcn_global_load_lds( \
    (const __attribute__((address_space(1))) void*)(g), \
    (__attribute__((address_space(3))) void*)(l), 16, 0, 0)

template<int NW>
__device__ inline float block_sum(float v, float* sbuf){
  #pragma unroll
  for (int mk=32; mk; mk>>=1) v += __shfl_xor(v, mk);
  int w = threadIdx.x>>6;
  if ((threadIdx.x&63)==0) sbuf[w]=v;
  __syncthreads();
  float r = 0.f;
  #pragma unroll
  for (int k=0;k<NW;k++) r += sbuf[k];
  __syncthreads();
  return r;
}

__device__ inline unsigned short bf16bits(float v){
  __hip_bfloat16 t = __float2bfloat16(v);
  unsigned short u;
  __builtin_memcpy(&u, &t, 2);
  return u;
}

// K2a: scorer k = m@sk_w + sk_b  (B,NT,D);  v = m@sv_w + sv_b (B,NT)
__global__ __launch_bounds__(256) void scorer_kv_kernel(
    const float* __restrict__ m, const float* __restrict__ sk_w,
    const float* __restrict__ sk_b, const float* __restrict__ sv_w,
    const float* __restrict__ sv_b, float* __restrict__ ksc, float* __restrict__ vsc)
{
  int bj = blockIdx.x;               // B*NT = 32
  int d = threadIdx.x;
  __shared__ float ms[256];
  __shared__ float sbuf[4];
  ms[d] = m[bj*DD + d];
  __syncthreads();
  float acc=0.f;
  for(int c=0;c<DD;c++) acc = fmaf(ms[c], sk_w[c*DD + d], acc);
  ksc[bj*DD + d] = acc + sk_b[d];
  float sv = block_sum<4>(ms[d]*sv_w[d], sbuf);
  if(d==0) vsc[bj] = sv + sv_b[0];
}

// K2b: kk2[b,j,c] = sum_d sq_w[c,d]*ksc[b,j,d];  kb[b,j] = sq_b . ksc[b,j]
__global__ __launch_bounds__(256) void kk2_kernel(
    const float* __restrict__ sq_w, const float* __restrict__ sq_b,
    const float* __restrict__ ksc, float* __restrict__ kk2, float* __restrict__ kb)
{
  int bj = blockIdx.x;               // 32
  int c = threadIdx.x;
  __shared__ float ks[256];
  __shared__ float sbuf[4];
  ks[c] = ksc[bj*DD + c];
  __syncthreads();
  const float* wr = sq_w + (long)c*DD;
  float acc = 0.f;
  for (int d=0; d<DD; d+=4){
    float4 wv = *(const float4*)(wr + d);
    acc = fmaf(wv.x, ks[d+0], acc);
    acc = fmaf(wv.y, ks[d+1], acc);
    acc = fmaf(wv.z, ks[d+2], acc);
    acc = fmaf(wv.w, ks[d+3], acc);
  }
  kk2[bj*DD + c] = acc;
  float kbv = block_sum<4>(sq_b[c]*ks[c], sbuf);
  if (c==0) kb[bj] = kbv;
}

// K1: tokens = LN(conv1x1(x)) AND scores via factored scorer. 16 tokens/block.
__global__ __launch_bounds__(256) void proj_ln_score_kernel(
    const float* __restrict__ x, const float* __restrict__ proj_w,
    const float* __restrict__ proj_b, const float* __restrict__ lnp_g,
    const float* __restrict__ lnp_b, const float* __restrict__ kk2,
    const float* __restrict__ kb, const float* __restrict__ vsc,
    float* __restrict__ tokens, float* __restrict__ scores)
{
  int b  = blockIdx.x >> 8;          // 256 blocks per batch
  int n0 = (blockIdx.x & 255) * 16;
  int tid = threadIdx.x;
  __shared__ float xs[16][132];
  __shared__ float ys[16][260];
  __shared__ float kj[8][260];
  __shared__ float kbs[8], vs[8];
  __shared__ float mu_s[16], rs_s[16];
  __shared__ float lg[16][8];
  #pragma unroll
  for (int i=0;i<8;i++){
    int l = tid + i*256;
    int t = l & 15, c = l >> 4;
    xs[t][c] = x[(long)(b*CC + c)*NN + n0 + t];
  }
  #pragma unroll
  for (int i=0;i<8;i++){
    int idx = i*256 + tid;
    int r = idx >> 8, c = idx & 255;
    kj[r][c] = kk2[(b*NT + r)*DD + c];
  }
  if (tid < 8){ kbs[tid] = kb[b*NT+tid]; vs[tid] = vsc[b*NT+tid]; }
  __syncthreads();
  float acc[16];
  #pragma unroll
  for (int t=0;t<16;t++) acc[t]=0.f;
  for (int c0=0;c0<CC;c0+=4){
    float w0 = proj_w[(c0+0)*DD + tid];
    float w1_ = proj_w[(c0+1)*DD + tid];
    float w2_ = proj_w[(c0+2)*DD + tid];
    float w3_ = proj_w[(c0+3)*DD + tid];
    #pragma unroll
    for (int t=0;t<16;t++){
      float4 xv = *(const float4*)&xs[t][c0];
      acc[t] = fmaf(xv.x,w0,fmaf(xv.y,w1_,fmaf(xv.z,w2_,fmaf(xv.w,w3_,acc[t]))));
    }
  }
  float pb = proj_b[tid];
  #pragma unroll
  for (int t=0;t<16;t++) ys[t][tid] = acc[t] + pb;
  __syncthreads();
  int w = tid>>6, lane = tid&63;
  for (int k=0;k<4;k++){
    int t = w*4+k;
    float s = ys[t][lane] + ys[t][lane+64] + ys[t][lane+128] + ys[t][lane+192];
    #pragma unroll
    for (int mk=32; mk; mk>>=1) s += __shfl_xor(s, mk);
    float mu = s*(1.0f/256.0f);
    float d0=ys[t][lane]-mu, d1=ys[t][lane+64]-mu, d2=ys[t][lane+128]-mu, d3=ys[t][lane+192]-mu;
    float q = d0*d0+d1*d1+d2*d2+d3*d3;
    #pragma unroll
    for (int mk=32; mk; mk>>=1) q += __shfl_xor(q, mk);
    if (lane==0){ mu_s[t]=mu; rs_s[t]=rsqrtf(q*(1.0f/256.0f)+1e-5f); }
  }
  __syncthreads();
  float g = lnp_g[tid], be = lnp_b[tid];
  #pragma unroll
  for (int t=0;t<16;t++){
    float nv = (ys[t][tid]-mu_s[t])*rs_s[t]*g + be;
    tokens[((long)(b*NN + n0 + t))*DD + tid] = nv;
    ys[t][tid] = nv;
  }
  __syncthreads();
  // factored logits: lg[t][j] = (ys[t].kj[j] + kb[j]) * SCALE
  if (tid < 128){
    int t = tid>>3, j = tid&7;
    float a2 = 0.f;
    for (int c0=0;c0<DD;c0+=4){
      float4 tv = *(const float4*)&ys[t][c0];
      float4 kv = *(const float4*)&kj[j][c0];
      a2 = fmaf(tv.x,kv.x,fmaf(tv.y,kv.y,fmaf(tv.z,kv.z,fmaf(tv.w,kv.w,a2))));
    }
    lg[t][j] = (a2 + kbs[j]) * SCALE;
  }
  __syncthreads();
  if (tid < 16){
    float mx=-1e30f;
    #pragma unroll
    for(int j=0;j<NT;j++) mx=fmaxf(mx,lg[tid][j]);
    float s=0.f, sc=0.f;
    #pragma unroll
    for(int j=0;j<NT;j++){ float e=__expf(lg[tid][j]-mx); s+=e; sc+=e*vs[j]; }
    scores[b*NN + n0 + tid] = sc/s;
  }
}

// K3a: partial ranks
__global__ __launch_bounds__(256) void rank_partial_kernel(
    const float* __restrict__ scores, int* __restrict__ rank)
{
  int b  = blockIdx.x >> 8;
  int it = (blockIdx.x >> 4) & 15;
  int jt = blockIdx.x & 15;
  int i = it*256 + threadIdx.x;
  float si = scores[b*NN + i];
  __shared__ float ss[256];
  ss[threadIdx.x] = scores[b*NN + jt*256 + threadIdx.x];
  __syncthreads();
  int jbase = jt*256;
  int cnt = 0;
  #pragma unroll 4
  for (int j=0;j<256;j++){
    float sj = ss[j];
    cnt += (sj > si) || (sj == si && (jbase+j) < i);
  }
  atomicAdd(&rank[b*NN+i], cnt);
}

// K3b: rank is a permutation -> slot = rank & (SS-1)
__global__ __launch_bounds__(256) void rank_finalize_kernel(
    const int* __restrict__ rank, int* __restrict__ cidx)
{
  int b = blockIdx.x >> 4;
  int i = (blockIdx.x & 15)*256 + threadIdx.x;
  int rk = rank[b*NN + i];
  int p = rk >> 10;
  cidx[(b*PP + p)*SS + (rk & (SS-1))] = i;
}

// K4: partition-mean scores + pw softmax, single block
__global__ __launch_bounds__(1024) void pscore_pw_kernel(
    const float* __restrict__ scores, const int* __restrict__ cidx,
    float* __restrict__ pw)
{
  __shared__ float ps[16];
  int wv = threadIdx.x>>6;         // 0..15 = (b,p)
  int lane = threadIdx.x&63;
  int b = wv>>2;
  float acc=0.f;
  for (int s=lane; s<SS; s+=64) acc += scores[b*NN + cidx[wv*SS + s]];
  #pragma unroll
  for (int mk=32; mk; mk>>=1) acc += __shfl_xor(acc, mk);
  if (lane==0) ps[wv] = acc*(1.0f/(float)SS);
  __syncthreads();
  if (threadIdx.x < BB){
    int bb = threadIdx.x;
    float mx=-1e30f;
    #pragma unroll
    for(int p=0;p<PP;p++) mx=fmaxf(mx,ps[bb*PP+p]);
    float s=0.f,e[PP];
    #pragma unroll
    for(int p=0;p<PP;p++){ e[p]=__expf(ps[bb*PP+p]-mx); s+=e[p]; }
    #pragma unroll
    for(int p=0;p<PP;p++) pw[bb*PP+p]=e[p]/s;
  }
}

// K6: gather + LN(an[p,0]) fused: write Xc (fp32 gathered) + actA (bf16 LN)
__global__ __launch_bounds__(256) void gather_ln_kernel(
    const float* __restrict__ tokens, const int* __restrict__ cidx,
    float* __restrict__ Xc, __hip_bfloat16* __restrict__ Y,
    const float* __restrict__ gamma, const float* __restrict__ beta)
{
  long slot = (long)blockIdx.x*8 + (threadIdx.x>>5);
  int l32 = threadIdx.x & 31;
  int b = (int)(slot >> 12);
  int p = (int)((slot>>10)&3);
  int i = cidx[slot];
  const float* src = tokens + ((long)b*NN + i)*DD + l32*8;
  float4 v0 = *(const float4*)src;
  float4 v1 = *(const float4*)(src+4);
  *(float4*)(Xc + slot*DD + l32*8) = v0;
  *(float4*)(Xc + slot*DD + l32*8 + 4) = v1;
  float s = v0.x+v0.y+v0.z+v0.w+v1.x+v1.y+v1.z+v1.w;
  #pragma unroll
  for (int mk=16; mk; mk>>=1) s += __shfl_xor(s, mk);
  float mu = s*(1.0f/256.0f);
  float vv[8] = {v0.x,v0.y,v0.z,v0.w,v1.x,v1.y,v1.z,v1.w};
  float q = 0.f;
  #pragma unroll
  for (int k=0;k<8;k++){ float d = vv[k]-mu; q += d*d; }
  #pragma unroll
  for (int mk=16; mk; mk>>=1) q += __shfl_xor(q, mk);
  float rs = rsqrtf(q*(1.0f/256.0f)+1e-5f);
  short8 o;
  #pragma unroll
  for (int k=0;k<8;k++){
    int d = l32*8+k;
    o[k] = (short)bf16bits((vv[k]-mu)*rs*gamma[p*(LL*DD)+d]+beta[p*(LL*DD)+d]);
  }
  *(short8*)(Y + slot*DD + l32*8) = o;
}

// K7: decoder K/V precompute; K stored transposed [pl,b][h][dh][j] for attn
__global__ __launch_bounds__(512) void kv_kernel(
    const float* __restrict__ m, const float* __restrict__ an_g,
    const float* __restrict__ an_b, const float* __restrict__ wk,
    const float* __restrict__ wv, float* __restrict__ kvkT, float* __restrict__ kvv)
{
  int idx = blockIdx.x;              // (pl*B + b)*NT + j, grid = 256
  int j = idx & 7, b = (idx>>3)&3, pl = idx>>5;
  int tid = threadIdx.x;
  __shared__ float mn[256];
  __shared__ float sbuf[8];
  float v = (tid<256) ? m[(b*NT+j)*DD + tid] : 0.0f;
  float s = block_sum<8>(v, sbuf);
  float mu = s*(1.0f/256.0f);
  float dv = (tid<256)? v-mu : 0.0f;
  float q = block_sum<8>(dv*dv, sbuf);
  float rs = rsqrtf(q*(1.0f/256.0f)+1e-5f);
  if (tid<256) mn[tid] = dv*rs*an_g[pl*DD+tid] + an_b[pl*DD+tid];
  __syncthreads();
  float ka=0.f, va=0.f;
  for (int c=0;c<DD;c++){
    float mc = mn[c];
    ka = fmaf(mc, wk[((long)pl*DD + c)*INNER + tid], ka);
    va = fmaf(mc, wv[((long)pl*DD + c)*INNER + tid], va);
  }
  // K transposed: [pl*B+b][h=tid>>6][dh=tid&63][j]
  kvkT[((long)pl*BB + b)*4096 + (tid>>6)*512 + (tid&63)*8 + j] = ka;
  kvv[(((long)pl*BB + b)*NT + j)*INNER + tid] = va;
}

// K8: rowwise LN -> bf16, 8 rows/block, vectorized
__global__ __launch_bounds__(256) void ln_rows_kernel(
    const float* __restrict__ X, __hip_bfloat16* __restrict__ Y,
    const float* __restrict__ gamma, const float* __restrict__ beta)
{
  long row = (long)blockIdx.x*8 + (threadIdx.x>>5);
  int l32 = threadIdx.x & 31;
  int p = (int)((row>>10)&3);
  const float* xr = X + row*DD + l32*8;
  float4 v0 = *(const float4*)xr;
  float4 v1 = *(const float4*)(xr+4);
  float s = v0.x+v0.y+v0.z+v0.w+v1.x+v1.y+v1.z+v1.w;
  #pragma unroll
  for (int mk=16; mk; mk>>=1) s += __shfl_xor(s, mk);
  float mu = s*(1.0f/256.0f);
  float vv[8] = {v0.x,v0.y,v0.z,v0.w,v1.x,v1.y,v1.z,v1.w};
  float q = 0.f;
  #pragma unroll
  for (int k=0;k<8;k++){ float d = vv[k]-mu; q += d*d; }
  #pragma unroll
  for (int mk=16; mk; mk>>=1) q += __shfl_xor(q, mk);
  float rs = rsqrtf(q*(1.0f/256.0f)+1e-5f);
  short8 o;
  #pragma unroll
  for (int k=0;k<8;k++){
    int d = l32*8+k;
    o[k] = (short)bf16bits((vv[k]-mu)*rs*gamma[p*(LL*DD)+d]+beta[p*(LL*DD)+d]);
  }
  *(short8*)(Y + row*DD + l32*8) = o;
}

// Kw: all 4 weight tensors -> bf16 transposed [pl][N][K], one launch
__global__ __launch_bounds__(256) void wconv_all_kernel(
    const float* __restrict__ wq, const float* __restrict__ wo,
    const float* __restrict__ w1, const float* __restrict__ w2,
    __hip_bfloat16* __restrict__ wqT, __hip_bfloat16* __restrict__ woT,
    __hip_bfloat16* __restrict__ w1T, __hip_bfloat16* __restrict__ w2T)
{
  int z = blockIdx.x;
  const float* src; __hip_bfloat16* dst; int K, N, rel;
  if (z < 256)      { src=wq; dst=wqT; K=DD;   N=INNER; rel=z; }
  else if (z < 512) { src=wo; dst=woT; K=INNER;N=DD;    rel=z-256; }
  else if (z < 1024){ src=w1; dst=w1T; K=DD;   N=FFD;   rel=z-512; }
  else              { src=w2; dst=w2T; K=FFD;  N=DD;    rel=z-1024; }
  int tn = N>>6, tk = K>>6, per = tn*tk;
  int pl = rel/per, r2 = rel%per;
  int n0 = (r2%tn)*64, k0 = (r2/tn)*64;
  __shared__ float t[64][65];
  int tid = threadIdx.x;
  #pragma unroll
  for (int i=0;i<16;i++){
    int idx = i*256+tid;
    int kk = idx>>6, nn = idx&63;
    t[kk][nn] = src[((long)pl*K + k0+kk)*N + n0+nn];
  }
  __syncthreads();
  #pragma unroll
  for (int i=0;i<16;i++){
    int idx = i*256+tid;
    int nn = idx>>6, kk = idx&63;
    dst[((long)pl*N + n0+nn)*K + k0+kk] = __float2bfloat16(t[kk][nn]);
  }
}

// K9: MFMA bf16 GEMM, 2-phase double-buffered (T3-min): stage(next) || compute(cur)
template<bool HASBIAS, bool GELU, bool ACCUM>
__global__ __launch_bounds__(256) void mfma_gemm(
    const __hip_bfloat16* __restrict__ A, long astride, int K,
    const __hip_bfloat16* __restrict__ BT, long bpstride,
    const float* __restrict__ bias, int bias_pstride,
    void* __restrict__ Cp, int ldc, long cstride)
{
  int g = blockIdx.z;
  int p = g & 3;
  const __hip_bfloat16* Ag = A  + (long)g*astride + (long)blockIdx.y*128*K;
  const __hip_bfloat16* Bg = BT + (long)p*bpstride + (long)blockIdx.x*128*K;
  const float* biasg = HASBIAS ? (bias + (long)p*bias_pstride) : nullptr;

  __shared__ __align__(16) __hip_bfloat16 Asm[2][128*64];
  __shared__ __align__(16) __hip_bfloat16 Bsm[2][128*64];

  int tid = threadIdx.x;
  int w = tid>>6, lane = tid&63;
  int wr = w>>1, wc = w&1;
  int lr = lane>>4, lc = lane&15;
  int ldsbase = tid & ~63;

  f32x4 acc[4][4] = {};
  int nt = K >> 6;

  #define STAGE(buf, k0) do { \
    _Pragma("unroll") \
    for (int i_=0;i_<4;i_++){ \
      int seg = i_*256 + tid; \
      int r = seg>>3, sl = seg&7; \
      int sg = sl ^ (r&7); \
      GLD_LDS16(Ag + (long)r*K + (k0) + sg*8, &Asm[buf][(i_*256 + ldsbase)*8]); \
    } \
    _Pragma("unroll") \
    for (int i_=0;i_<4;i_++){ \
      int seg = i_*256 + tid; \
      int r = seg>>3, sl = seg&7; \
      int sg = sl ^ (r&7); \
      GLD_LDS16(Bg + (long)r*K + (k0) + sg*8, &Bsm[buf][(i_*256 + ldsbase)*8]); \
    } \
  } while(0)

  STAGE(0, 0);
  asm volatile("s_waitcnt vmcnt(0)" ::: "memory");
  __syncthreads();

  for (int t=0; t<nt; t++){
    int cur = t & 1;
    if (t+1 < nt) STAGE(cur^1, (t+1)<<6);
    #pragma unroll
    for (int kc=0;kc<2;kc++){
      bf16x8 af[4], bfr[4];
      #pragma unroll
      for (int mi=0;mi<4;mi++){
        int r = wr*64 + mi*16 + lc;
        int s = kc*4 + lr;
        af[mi] = *(const bf16x8*)(&Asm[cur][r*64 + (s ^ (r&7))*8]);
      }
      #pragma unroll
      for (int ni=0;ni<4;ni++){
        int r = wc*64 + ni*16 + lc;
        int s = kc*4 + lr;
        bfr[ni] = *(const bf16x8*)(&Bsm[cur][r*64 + (s ^ (r&7))*8]);
      }
      #pragma unroll
      for (int mi=0;mi<4;mi++)
        #pragma unroll
        for (int ni=0;ni<4;ni++)
          acc[mi][ni] = __builtin_amdgcn_mfma_f32_16x16x32_bf16(af[mi], bfr[ni], acc[mi][ni], 0, 0, 0);
    }
    if (t+1 < nt) asm volatile("s_waitcnt vmcnt(0)" ::: "memory");
    __syncthreads();
  }
  #undef STAGE

  if (ACCUM){
    float* Cg = (float*)Cp + (long)g*cstride;
    #pragma unroll
    for (int ni=0;ni<4;ni++){
      int col = blockIdx.x*128 + wc*64 + ni*16 + lc;
      float bv = HASBIAS ? biasg[col] : 0.0f;
      #pragma unroll
      for (int mi=0;mi<4;mi++){
        int row = blockIdx.y*128 + wr*64 + mi*16 + lr*4;
        #pragma unroll
        for (int j=0;j<4;j++){
          float v = acc[mi][ni][j] + bv;
          if (GELU) v = 0.5f*v*(1.0f+erff(v*0.70710678118654752440f));
          Cg[(long)(row+j)*ldc + col] += v;
        }
      }
    }
  } else {
    __hip_bfloat16* Cg = (__hip_bfloat16*)Cp + (long)g*cstride;
    #pragma unroll
    for (int ni=0;ni<4;ni++){
      int col = blockIdx.x*128 + wc*64 + ni*16 + lc;
      float bv = HASBIAS ? biasg[col] : 0.0f;
      #pragma unroll
      for (int mi=0;mi<4;mi++){
        int row = blockIdx.y*128 + wr*64 + mi*16 + lr*4;
        #pragma unroll
        for (int j=0;j<4;j++){
          float v = acc[mi][ni][j] + bv;
          if (GELU) v = 0.5f*v*(1.0f+erff(v*0.70710678118654752440f));
          Cg[(long)(row+j)*ldc + col] = __float2bfloat16(v);
        }
      }
    }
  }
}

// K10: 8-head/8-slot attention; in-place on bf16 Q; K from transposed cache
__global__ __launch_bounds__(256) void attn_kernel(
    __hip_bfloat16* __restrict__ QO, const float* __restrict__ kvkT,
    const float* __restrict__ kvv, int l)
{
  __shared__ float q_sm[4][8][68];
  int w = threadIdx.x>>6, lane = threadIdx.x&63;
  long tg = (long)blockIdx.x*4 + w;
  int g = (int)(tg>>10); int b = g>>2, p = g&3;
  long kvbase = (long)((p*LL+l)*BB + b);
  const __hip_bfloat16* Q = QO + tg*INNER;
  #pragma unroll
  for (int i=0;i<8;i++) q_sm[w][i][lane] = __bfloat162float(Q[i*64+lane]);
  __syncthreads();
  int h = lane>>3, j = lane&7;
  const float* kp = kvkT + kvbase*4096 + h*512 + j;
  float acc=0.f;
  #pragma unroll
  for (int dh=0;dh<64;dh++) acc = fmaf(q_sm[w][h][dh], kp[dh*8], acc);
  acc *= SCALE;
  float mx = acc;
  mx = fmaxf(mx, __shfl_xor(mx,1));
  mx = fmaxf(mx, __shfl_xor(mx,2));
  mx = fmaxf(mx, __shfl_xor(mx,4));
  float e = __expf(acc-mx);
  float s = e;
  s += __shfl_xor(s,1); s += __shfl_xor(s,2); s += __shfl_xor(s,4);
  float a = e/s;
  float o[8] = {0,0,0,0,0,0,0,0};
  #pragma unroll
  for (int jj=0;jj<8;jj++){
    float aj = __shfl(a, (lane&56)+jj);
    const float* vp = kvv + (kvbase*NT + jj)*INNER + lane*8;
    #pragma unroll
    for (int qi=0;qi<8;qi++) o[qi] = fmaf(aj, vp[qi], o[qi]);
  }
  __hip_bfloat16* Op = QO + tg*INNER + lane*8;
  #pragma unroll
  for (int qi=0;qi<8;qi++) Op[qi] = __float2bfloat16(o[qi]);
}

// K11: scale by pw, final LN, scatter; 8 rows/block
__global__ __launch_bounds__(256) void final_kernel(
    const float* __restrict__ Xc, const int* __restrict__ cidx,
    const float* __restrict__ pw, const float* __restrict__ fln_g,
    const float* __restrict__ fln_b, float* __restrict__ out)
{
  long slot = (long)blockIdx.x*8 + (threadIdx.x>>5);
  int l32 = threadIdx.x & 31;
  int b = (int)(slot>>12);
  int p = (int)((slot>>10)&3);
  int i = cidx[slot];
  float pwv = pw[b*PP+p];
  const float* xr = Xc + slot*DD + l32*8;
  float4 v0 = *(const float4*)xr;
  float4 v1 = *(const float4*)(xr+4);
  float vv[8] = {v0.x,v0.y,v0.z,v0.w,v1.x,v1.y,v1.z,v1.w};
  #pragma unroll
  for (int k=0;k<8;k++) vv[k] *= pwv;
  float s = 0.f;
  #pragma unroll
  for (int k=0;k<8;k++) s += vv[k];
  #pragma unroll
  for (int mk=16; mk; mk>>=1) s += __shfl_xor(s, mk);
  float mu = s*(1.0f/256.0f);
  float q = 0.f;
  #pragma unroll
  for (int k=0;k<8;k++){ float d = vv[k]-mu; q += d*d; }
  #pragma unroll
  for (int mk=16; mk; mk>>=1) q += __shfl_xor(q, mk);
  float rs = rsqrtf(q*(1.0f/256.0f)+1e-5f);
  float* op = out + ((long)b*NN+i)*DD + l32*8;
  float4 o0, o1;
  o0.x = (vv[0]-mu)*rs*fln_g[l32*8+0]+fln_b[l32*8+0];
  o0.y = (vv[1]-mu)*rs*fln_g[l32*8+1]+fln_b[l32*8+1];
  o0.z = (vv[2]-mu)*rs*fln_g[l32*8+2]+fln_b[l32*8+2];
  o0.w = (vv[3]-mu)*rs*fln_g[l32*8+3]+fln_b[l32*8+3];
  o1.x = (vv[4]-mu)*rs*fln_g[l32*8+4]+fln_b[l32*8+4];
  o1.y = (vv[5]-mu)*rs*fln_g[l32*8+5]+fln_b[l32*8+5];
  o1.z = (vv[6]-mu)*rs*fln_g[l32*8+6]+fln_b[l32*8+6];
  o1.w = (vv[7]-mu)*rs*fln_g[l32*8+7]+fln_b[l32*8+7];
  *(float4*)op = o0;
  *(float4*)(op+4) = o1;
}

extern "C" void kernel_launch(void* const* d_in, const int* in_sizes, int n_in,
                              void* d_out, int out_size, void* d_ws, size_t ws_size,
                              hipStream_t stream)
{
  (void)in_sizes; (void)n_in; (void)out_size; (void)ws_size;
  const float* x     =(const float*)d_in[0];
  const float* m     =(const float*)d_in[1];
  const float* proj_w=(const float*)d_in[2];
  const float* proj_b=(const float*)d_in[3];
  const float* lnp_g =(const float*)d_in[4];
  const float* lnp_b =(const float*)d_in[5];
  const float* sq_w  =(const float*)d_in[6];
  const float* sq_b  =(const float*)d_in[7];
  const float* sk_w  =(const float*)d_in[8];
  const float* sk_b  =(const float*)d_in[9];
  const float* sv_w  =(const float*)d_in[10];
  const float* sv_b  =(const float*)d_in[11];
  const float* an_g  =(const float*)d_in[12];
  const float* an_b  =(const float*)d_in[13];
  const float* wq    =(const float*)d_in[14];
  const float* wk    =(const float*)d_in[15];
  const float* wv    =(const float*)d_in[16];
  const float* wo    =(const float*)d_in[17];
  const float* wo_b  =(const float*)d_in[18];
  const float* fn_g  =(const float*)d_in[19];
  const float* fn_b  =(const float*)d_in[20];
  const float* w1    =(const float*)d_in[21];
  const float* b1    =(const float*)d_in[22];
  const float* w2    =(const float*)d_in[23];
  const float* b2    =(const float*)d_in[24];
  const float* fln_g =(const float*)d_in[25];
  const float* fln_b =(const float*)d_in[26];
  float* out = (float*)d_out;

  float* ws = (float*)d_ws;
  float* tokens = ws;  ws += 4194304;   // 16 MB; first half of actF alias
  float* actQf  = ws;  ws += 4194304;   // actQ bf16 (16384x512); 2nd half of actF
  float* Xc     = ws;  ws += 4194304;   // fp32 residual
  float* actAf  = ws;  ws += 2097152;   // actA bf16 (16384x256)
  float* wqTf   = ws;  ws += 524288;
  float* woTf   = ws;  ws += 524288;
  float* w1Tf   = ws;  ws += 1048576;
  float* w2Tf   = ws;  ws += 1048576;
  float* kvkT   = ws;  ws += 131072;
  float* kvv    = ws;  ws += 131072;
  float* ksc    = ws;  ws += 8192;
  float* vsc    = ws;  ws += 64;
  float* kk2    = ws;  ws += 8192;
  float* kb     = ws;  ws += 32;
  float* scores = ws;  ws += 16384;
  float* pw     = ws;  ws += 16;
  int* rank     = (int*)ws;  ws += 16384;
  int* cidx     = (int*)ws;  ws += 16384;

  __hip_bfloat16* actA = (__hip_bfloat16*)actAf;
  __hip_bfloat16* actQ = (__hip_bfloat16*)actQf;
  __hip_bfloat16* actF = (__hip_bfloat16*)tokens;
  __hip_bfloat16* wqT  = (__hip_bfloat16*)wqTf;
  __hip_bfloat16* woT  = (__hip_bfloat16*)woTf;
  __hip_bfloat16* w1T  = (__hip_bfloat16*)w1Tf;
  __hip_bfloat16* w2T  = (__hip_bfloat16*)w2Tf;

  hipMemsetAsync(rank, 0, BB*NN*sizeof(int), stream);
  scorer_kv_kernel<<<32,256,0,stream>>>(m, sk_w, sk_b, sv_w, sv_b, ksc, vsc);
  kk2_kernel<<<32,256,0,stream>>>(sq_w, sq_b, ksc, kk2, kb);
  proj_ln_score_kernel<<<1024,256,0,stream>>>(x, proj_w, proj_b, lnp_g, lnp_b,
                                              kk2, kb, vsc, tokens, scores);
  rank_partial_kernel<<<1024,256,0,stream>>>(scores, rank);
  rank_finalize_kernel<<<64,256,0,stream>>>(rank, cidx);
  pscore_pw_kernel<<<1,1024,0,stream>>>(scores, cidx, pw);
  kv_kernel<<<256,512,0,stream>>>(m, an_g, an_b, wk, wv, kvkT, kvv);
  wconv_all_kernel<<<1536,256,0,stream>>>(wq, wo, w1, w2, wqT, woT, w1T, w2T);
  gather_ln_kernel<<<2048,256,0,stream>>>(tokens, cidx, Xc, actA, an_g, an_b);

  for (int l=0;l<LL;l++){
    if (l > 0)
      ln_rows_kernel<<<2048,256,0,stream>>>(Xc, actA, an_g + l*DD, an_b + l*DD);
    // Q = xn @ wq[p,l]
    mfma_gemm<false,false,false><<<dim3(4,8,16),256,0,stream>>>(
        actA, (long)SS*DD, DD, wqT + (long)l*INNER*DD, (long)LL*INNER*DD,
        nullptr, 0, actQ, INNER, (long)SS*INNER);
    attn_kernel<<<4096,256,0,stream>>>(actQ, kvkT, kvv, l);
    // Xc += AO @ wo[p,l] + wo_b
    mfma_gemm<true,false,true><<<dim3(2,8,16),256,0,stream>>>(
        actQ, (long)SS*INNER, INNER, woT + (long)l*DD*INNER, (long)LL*DD*INNER,
        wo_b + l*DD, LL*DD, Xc, DD, (long)SS*DD);
    ln_rows_kernel<<<2048,256,0,stream>>>(Xc, actA, fn_g + l*DD, fn_b + l*DD);
    // F = gelu(h @ w1 + b1)
    mfma_gemm<true,true,false><<<dim3(8,8,16),256,0,stream>>>(
        actA, (long)SS*DD, DD, w1T + (long)l*FFD*DD, (long)LL*FFD*DD,
        b1 + l*FFD, LL*FFD, actF, FFD, (long)SS*FFD);
    // Xc += F @ w2 + b2
    mfma_gemm<true,false,true><<<dim3(2,8,16),256,0,stream>>>(
        actF, (long)SS*FFD, FFD, w2T + (long)l*DD*FFD, (long)LL*DD*FFD,
        b2 + l*DD, LL*DD, Xc, DD, (long)SS*DD);
  }
  final_kernel<<<2048,256,0,stream>>>(Xc, cidx, pw, fln_g, fln_b, out);
}

// Round 8
// 386.612 us; speedup vs baseline: 3.5636x; 1.0804x over previous
//
#include <hip/hip_runtime.h>
#include <hip/hip_bf16.h>
#include <math.h>

// Problem constants
#define BB 4
#define CC 128
#define NN 4096      // H*W
#define DD 256
#define INNER 512
#define FFD 1024
#define PP 4
#define LL 2
#define NT 8
#define SS 1024      // NN/PP
#define SCALE 0.0625f // 1/sqrt(256)

typedef __attribute__((ext_vector_type(8))) short bf16x8;
typedef __attribute__((ext_vector_type(8))) short short8;
typedef __attribute__((ext_vector_type(4))) float f32x4;

#define GLD_LDS16(g, l) __builtin_amdgcn_global_load_lds( \
    (const __attribute__((address_space(1))) void*)(g), \
    (__attribute__((address_space(3))) void*)(l), 16, 0, 0)

template<int NW>
__device__ inline float block_sum(float v, float* sbuf){
  #pragma unroll
  for (int mk=32; mk; mk>>=1) v += __shfl_xor(v, mk);
  int w = threadIdx.x>>6;
  if ((threadIdx.x&63)==0) sbuf[w]=v;
  __syncthreads();
  float r = 0.f;
  #pragma unroll
  for (int k=0;k<NW;k++) r += sbuf[k];
  __syncthreads();
  return r;
}

__device__ inline unsigned short bf16bits(float v){
  __hip_bfloat16 t = __float2bfloat16(v);
  unsigned short u;
  __builtin_memcpy(&u, &t, 2);
  return u;
}

// fast GELU: erf via Abramowitz-Stegun 7.1.26 (|eps| <= 1.5e-7)
__device__ inline float gelu_f(float x){
  float z  = x * 0.70710678118654752440f;
  float az = fabsf(z);
  float t  = 1.0f / (1.0f + 0.3275911f*az);
  float y  = t*(0.254829592f + t*(-0.284496736f + t*(1.421413741f +
             t*(-1.453152027f + t*1.061405429f))));
  float erfv = 1.0f - y*__expf(-az*az);
  erfv = (z < 0.0f) ? -erfv : erfv;
  return 0.5f*x*(1.0f+erfv);
}

// K2a: scorer k = m@sk_w + sk_b  (B,NT,D);  v = m@sv_w + sv_b (B,NT)
__global__ __launch_bounds__(256) void scorer_kv_kernel(
    const float* __restrict__ m, const float* __restrict__ sk_w,
    const float* __restrict__ sk_b, const float* __restrict__ sv_w,
    const float* __restrict__ sv_b, float* __restrict__ ksc, float* __restrict__ vsc)
{
  int bj = blockIdx.x;               // B*NT = 32
  int d = threadIdx.x;
  __shared__ float ms[256];
  __shared__ float sbuf[4];
  ms[d] = m[bj*DD + d];
  __syncthreads();
  float acc=0.f;
  for(int c=0;c<DD;c++) acc = fmaf(ms[c], sk_w[c*DD + d], acc);
  ksc[bj*DD + d] = acc + sk_b[d];
  float sv = block_sum<4>(ms[d]*sv_w[d], sbuf);
  if(d==0) vsc[bj] = sv + sv_b[0];
}

// K2b: kk2[b,j,c] = sum_d sq_w[c,d]*ksc[b,j,d];  kb[b,j] = sq_b . ksc[b,j]
__global__ __launch_bounds__(256) void kk2_kernel(
    const float* __restrict__ sq_w, const float* __restrict__ sq_b,
    const float* __restrict__ ksc, float* __restrict__ kk2, float* __restrict__ kb)
{
  int bj = blockIdx.x;               // 32
  int c = threadIdx.x;
  __shared__ float ks[256];
  __shared__ float sbuf[4];
  ks[c] = ksc[bj*DD + c];
  __syncthreads();
  const float* wr = sq_w + (long)c*DD;
  float acc = 0.f;
  for (int d=0; d<DD; d+=4){
    float4 wv = *(const float4*)(wr + d);
    acc = fmaf(wv.x, ks[d+0], acc);
    acc = fmaf(wv.y, ks[d+1], acc);
    acc = fmaf(wv.z, ks[d+2], acc);
    acc = fmaf(wv.w, ks[d+3], acc);
  }
  kk2[bj*DD + c] = acc;
  float kbv = block_sum<4>(sq_b[c]*ks[c], sbuf);
  if (c==0) kb[bj] = kbv;
}

// K1: tokens = LN(conv1x1(x)) AND scores via factored scorer. 16 tokens/block.
__global__ __launch_bounds__(256) void proj_ln_score_kernel(
    const float* __restrict__ x, const float* __restrict__ proj_w,
    const float* __restrict__ proj_b, const float* __restrict__ lnp_g,
    const float* __restrict__ lnp_b, const float* __restrict__ kk2,
    const float* __restrict__ kb, const float* __restrict__ vsc,
    float* __restrict__ tokens, float* __restrict__ scores)
{
  int b  = blockIdx.x >> 8;          // 256 blocks per batch
  int n0 = (blockIdx.x & 255) * 16;
  int tid = threadIdx.x;
  __shared__ float xs[16][132];
  __shared__ float ys[16][260];
  __shared__ float kj[8][260];
  __shared__ float kbs[8], vs[8];
  __shared__ float mu_s[16], rs_s[16];
  __shared__ float lg[16][8];
  #pragma unroll
  for (int i=0;i<8;i++){
    int l = tid + i*256;
    int t = l & 15, c = l >> 4;
    xs[t][c] = x[(long)(b*CC + c)*NN + n0 + t];
  }
  #pragma unroll
  for (int i=0;i<8;i++){
    int idx = i*256 + tid;
    int r = idx >> 8, c = idx & 255;
    kj[r][c] = kk2[(b*NT + r)*DD + c];
  }
  if (tid < 8){ kbs[tid] = kb[b*NT+tid]; vs[tid] = vsc[b*NT+tid]; }
  __syncthreads();
  float acc[16];
  #pragma unroll
  for (int t=0;t<16;t++) acc[t]=0.f;
  for (int c0=0;c0<CC;c0+=4){
    float w0 = proj_w[(c0+0)*DD + tid];
    float w1_ = proj_w[(c0+1)*DD + tid];
    float w2_ = proj_w[(c0+2)*DD + tid];
    float w3_ = proj_w[(c0+3)*DD + tid];
    #pragma unroll
    for (int t=0;t<16;t++){
      float4 xv = *(const float4*)&xs[t][c0];
      acc[t] = fmaf(xv.x,w0,fmaf(xv.y,w1_,fmaf(xv.z,w2_,fmaf(xv.w,w3_,acc[t]))));
    }
  }
  float pb = proj_b[tid];
  #pragma unroll
  for (int t=0;t<16;t++) ys[t][tid] = acc[t] + pb;
  __syncthreads();
  int w = tid>>6, lane = tid&63;
  for (int k=0;k<4;k++){
    int t = w*4+k;
    float s = ys[t][lane] + ys[t][lane+64] + ys[t][lane+128] + ys[t][lane+192];
    #pragma unroll
    for (int mk=32; mk; mk>>=1) s += __shfl_xor(s, mk);
    float mu = s*(1.0f/256.0f);
    float d0=ys[t][lane]-mu, d1=ys[t][lane+64]-mu, d2=ys[t][lane+128]-mu, d3=ys[t][lane+192]-mu;
    float q = d0*d0+d1*d1+d2*d2+d3*d3;
    #pragma unroll
    for (int mk=32; mk; mk>>=1) q += __shfl_xor(q, mk);
    if (lane==0){ mu_s[t]=mu; rs_s[t]=rsqrtf(q*(1.0f/256.0f)+1e-5f); }
  }
  __syncthreads();
  float g = lnp_g[tid], be = lnp_b[tid];
  #pragma unroll
  for (int t=0;t<16;t++){
    float nv = (ys[t][tid]-mu_s[t])*rs_s[t]*g + be;
    tokens[((long)(b*NN + n0 + t))*DD + tid] = nv;
    ys[t][tid] = nv;
  }
  __syncthreads();
  // factored logits: lg[t][j] = (ys[t].kj[j] + kb[j]) * SCALE
  if (tid < 128){
    int t = tid>>3, j = tid&7;
    float a2 = 0.f;
    for (int c0=0;c0<DD;c0+=4){
      float4 tv = *(const float4*)&ys[t][c0];
      float4 kv = *(const float4*)&kj[j][c0];
      a2 = fmaf(tv.x,kv.x,fmaf(tv.y,kv.y,fmaf(tv.z,kv.z,fmaf(tv.w,kv.w,a2))));
    }
    lg[t][j] = (a2 + kbs[j]) * SCALE;
  }
  __syncthreads();
  if (tid < 16){
    float mx=-1e30f;
    #pragma unroll
    for(int j=0;j<NT;j++) mx=fmaxf(mx,lg[tid][j]);
    float s=0.f, sc=0.f;
    #pragma unroll
    for(int j=0;j<NT;j++){ float e=__expf(lg[tid][j]-mx); s+=e; sc+=e*vs[j]; }
    scores[b*NN + n0 + tid] = sc/s;
  }
}

// K3a: partial ranks
__global__ __launch_bounds__(256) void rank_partial_kernel(
    const float* __restrict__ scores, int* __restrict__ rank)
{
  int b  = blockIdx.x >> 8;
  int it = (blockIdx.x >> 4) & 15;
  int jt = blockIdx.x & 15;
  int i = it*256 + threadIdx.x;
  float si = scores[b*NN + i];
  __shared__ float ss[256];
  ss[threadIdx.x] = scores[b*NN + jt*256 + threadIdx.x];
  __syncthreads();
  int jbase = jt*256;
  int cnt = 0;
  #pragma unroll 4
  for (int j=0;j<256;j++){
    float sj = ss[j];
    cnt += (sj > si) || (sj == si && (jbase+j) < i);
  }
  atomicAdd(&rank[b*NN+i], cnt);
}

// K3b: rank is a permutation -> slot = rank & (SS-1)
__global__ __launch_bounds__(256) void rank_finalize_kernel(
    const int* __restrict__ rank, int* __restrict__ cidx)
{
  int b = blockIdx.x >> 4;
  int i = (blockIdx.x & 15)*256 + threadIdx.x;
  int rk = rank[b*NN + i];
  int p = rk >> 10;
  cidx[(b*PP + p)*SS + (rk & (SS-1))] = i;
}

// K4: partition-mean scores + pw softmax, single block
__global__ __launch_bounds__(1024) void pscore_pw_kernel(
    const float* __restrict__ scores, const int* __restrict__ cidx,
    float* __restrict__ pw)
{
  __shared__ float ps[16];
  int wv = threadIdx.x>>6;         // 0..15 = (b,p)
  int lane = threadIdx.x&63;
  int b = wv>>2;
  float acc=0.f;
  for (int s=lane; s<SS; s+=64) acc += scores[b*NN + cidx[wv*SS + s]];
  #pragma unroll
  for (int mk=32; mk; mk>>=1) acc += __shfl_xor(acc, mk);
  if (lane==0) ps[wv] = acc*(1.0f/(float)SS);
  __syncthreads();
  if (threadIdx.x < BB){
    int bb = threadIdx.x;
    float mx=-1e30f;
    #pragma unroll
    for(int p=0;p<PP;p++) mx=fmaxf(mx,ps[bb*PP+p]);
    float s=0.f,e[PP];
    #pragma unroll
    for(int p=0;p<PP;p++){ e[p]=__expf(ps[bb*PP+p]-mx); s+=e[p]; }
    #pragma unroll
    for(int p=0;p<PP;p++) pw[bb*PP+p]=e[p]/s;
  }
}

// K6: gather + LN(an[p,0]) fused: write Xc (fp32 gathered) + actA (bf16 LN)
__global__ __launch_bounds__(256) void gather_ln_kernel(
    const float* __restrict__ tokens, const int* __restrict__ cidx,
    float* __restrict__ Xc, __hip_bfloat16* __restrict__ Y,
    const float* __restrict__ gamma, const float* __restrict__ beta)
{
  long slot = (long)blockIdx.x*8 + (threadIdx.x>>5);
  int l32 = threadIdx.x & 31;
  int b = (int)(slot >> 12);
  int p = (int)((slot>>10)&3);
  int i = cidx[slot];
  const float* src = tokens + ((long)b*NN + i)*DD + l32*8;
  float4 v0 = *(const float4*)src;
  float4 v1 = *(const float4*)(src+4);
  *(float4*)(Xc + slot*DD + l32*8) = v0;
  *(float4*)(Xc + slot*DD + l32*8 + 4) = v1;
  float s = v0.x+v0.y+v0.z+v0.w+v1.x+v1.y+v1.z+v1.w;
  #pragma unroll
  for (int mk=16; mk; mk>>=1) s += __shfl_xor(s, mk);
  float mu = s*(1.0f/256.0f);
  float vv[8] = {v0.x,v0.y,v0.z,v0.w,v1.x,v1.y,v1.z,v1.w};
  float q = 0.f;
  #pragma unroll
  for (int k=0;k<8;k++){ float d = vv[k]-mu; q += d*d; }
  #pragma unroll
  for (int mk=16; mk; mk>>=1) q += __shfl_xor(q, mk);
  float rs = rsqrtf(q*(1.0f/256.0f)+1e-5f);
  short8 o;
  #pragma unroll
  for (int k=0;k<8;k++){
    int d = l32*8+k;
    o[k] = (short)bf16bits((vv[k]-mu)*rs*gamma[p*(LL*DD)+d]+beta[p*(LL*DD)+d]);
  }
  *(short8*)(Y + slot*DD + l32*8) = o;
}

// K7: decoder K/V precompute; K stored transposed [pl,b][h][dh][j] for attn
__global__ __launch_bounds__(512) void kv_kernel(
    const float* __restrict__ m, const float* __restrict__ an_g,
    const float* __restrict__ an_b, const float* __restrict__ wk,
    const float* __restrict__ wv, float* __restrict__ kvkT, float* __restrict__ kvv)
{
  int idx = blockIdx.x;              // (pl*B + b)*NT + j, grid = 256
  int j = idx & 7, b = (idx>>3)&3, pl = idx>>5;
  int tid = threadIdx.x;
  __shared__ float mn[256];
  __shared__ float sbuf[8];
  float v = (tid<256) ? m[(b*NT+j)*DD + tid] : 0.0f;
  float s = block_sum<8>(v, sbuf);
  float mu = s*(1.0f/256.0f);
  float dv = (tid<256)? v-mu : 0.0f;
  float q = block_sum<8>(dv*dv, sbuf);
  float rs = rsqrtf(q*(1.0f/256.0f)+1e-5f);
  if (tid<256) mn[tid] = dv*rs*an_g[pl*DD+tid] + an_b[pl*DD+tid];
  __syncthreads();
  float ka=0.f, va=0.f;
  for (int c=0;c<DD;c++){
    float mc = mn[c];
    ka = fmaf(mc, wk[((long)pl*DD + c)*INNER + tid], ka);
    va = fmaf(mc, wv[((long)pl*DD + c)*INNER + tid], va);
  }
  // K transposed: [pl*B+b][h=tid>>6][dh=tid&63][j]
  kvkT[((long)pl*BB + b)*4096 + (tid>>6)*512 + (tid&63)*8 + j] = ka;
  kvv[(((long)pl*BB + b)*NT + j)*INNER + tid] = va;
}

// K8: rowwise LN -> bf16, 8 rows/block, vectorized
__global__ __launch_bounds__(256) void ln_rows_kernel(
    const float* __restrict__ X, __hip_bfloat16* __restrict__ Y,
    const float* __restrict__ gamma, const float* __restrict__ beta)
{
  long row = (long)blockIdx.x*8 + (threadIdx.x>>5);
  int l32 = threadIdx.x & 31;
  int p = (int)((row>>10)&3);
  const float* xr = X + row*DD + l32*8;
  float4 v0 = *(const float4*)xr;
  float4 v1 = *(const float4*)(xr+4);
  float s = v0.x+v0.y+v0.z+v0.w+v1.x+v1.y+v1.z+v1.w;
  #pragma unroll
  for (int mk=16; mk; mk>>=1) s += __shfl_xor(s, mk);
  float mu = s*(1.0f/256.0f);
  float vv[8] = {v0.x,v0.y,v0.z,v0.w,v1.x,v1.y,v1.z,v1.w};
  float q = 0.f;
  #pragma unroll
  for (int k=0;k<8;k++){ float d = vv[k]-mu; q += d*d; }
  #pragma unroll
  for (int mk=16; mk; mk>>=1) q += __shfl_xor(q, mk);
  float rs = rsqrtf(q*(1.0f/256.0f)+1e-5f);
  short8 o;
  #pragma unroll
  for (int k=0;k<8;k++){
    int d = l32*8+k;
    o[k] = (short)bf16bits((vv[k]-mu)*rs*gamma[p*(LL*DD)+d]+beta[p*(LL*DD)+d]);
  }
  *(short8*)(Y + row*DD + l32*8) = o;
}

// Kw: all 4 weight tensors -> bf16 transposed [pl][N][K], one launch
__global__ __launch_bounds__(256) void wconv_all_kernel(
    const float* __restrict__ wq, const float* __restrict__ wo,
    const float* __restrict__ w1, const float* __restrict__ w2,
    __hip_bfloat16* __restrict__ wqT, __hip_bfloat16* __restrict__ woT,
    __hip_bfloat16* __restrict__ w1T, __hip_bfloat16* __restrict__ w2T)
{
  int z = blockIdx.x;
  const float* src; __hip_bfloat16* dst; int K, N, rel;
  if (z < 256)      { src=wq; dst=wqT; K=DD;   N=INNER; rel=z; }
  else if (z < 512) { src=wo; dst=woT; K=INNER;N=DD;    rel=z-256; }
  else if (z < 1024){ src=w1; dst=w1T; K=DD;   N=FFD;   rel=z-512; }
  else              { src=w2; dst=w2T; K=FFD;  N=DD;    rel=z-1024; }
  int tn = N>>6, tk = K>>6, per = tn*tk;
  int pl = rel/per, r2 = rel%per;
  int n0 = (r2%tn)*64, k0 = (r2/tn)*64;
  __shared__ float t[64][65];
  int tid = threadIdx.x;
  #pragma unroll
  for (int i=0;i<16;i++){
    int idx = i*256+tid;
    int kk = idx>>6, nn = idx&63;
    t[kk][nn] = src[((long)pl*K + k0+kk)*N + n0+nn];
  }
  __syncthreads();
  #pragma unroll
  for (int i=0;i<16;i++){
    int idx = i*256+tid;
    int nn = idx>>6, kk = idx&63;
    dst[((long)pl*N + n0+nn)*K + k0+kk] = __float2bfloat16(t[kk][nn]);
  }
}

// K9: MFMA bf16 GEMM, 2-phase double-buffered. Grid: (rowTiles=8, colTiles, g=16)
// rowTile = blockIdx.x (FASTEST) -> XCD i owns row-panel i: A panel L2-resident per XCD.
template<bool HASBIAS, bool GELU, bool ACCUM>
__global__ __launch_bounds__(256) void mfma_gemm(
    const __hip_bfloat16* __restrict__ A, long astride, int K,
    const __hip_bfloat16* __restrict__ BT, long bpstride,
    const float* __restrict__ bias, int bias_pstride,
    void* __restrict__ Cp, int ldc, long cstride)
{
  int g = blockIdx.z;
  int p = g & 3;
  const __hip_bfloat16* Ag = A  + (long)g*astride + (long)blockIdx.x*128*K;
  const __hip_bfloat16* Bg = BT + (long)p*bpstride + (long)blockIdx.y*128*K;
  const float* biasg = HASBIAS ? (bias + (long)p*bias_pstride) : nullptr;

  __shared__ __align__(16) __hip_bfloat16 Asm[2][128*64];
  __shared__ __align__(16) __hip_bfloat16 Bsm[2][128*64];

  int tid = threadIdx.x;
  int w = tid>>6, lane = tid&63;
  int wr = w>>1, wc = w&1;
  int lr = lane>>4, lc = lane&15;
  int ldsbase = tid & ~63;

  // precomputed, self-advancing global segment pointers (swizzled source)
  const __hip_bfloat16* aseg[4];
  const __hip_bfloat16* bseg[4];
  #pragma unroll
  for (int i=0;i<4;i++){
    int seg = i*256 + tid;
    int r = seg>>3, sl = seg&7;
    int sg = sl ^ (r&7);
    aseg[i] = Ag + (long)r*K + sg*8;
    bseg[i] = Bg + (long)r*K + sg*8;
  }

  f32x4 acc[4][4] = {};
  int nt = K >> 6;

  #define STAGE(buf) do { \
    _Pragma("unroll") \
    for (int i_=0;i_<4;i_++) \
      GLD_LDS16(aseg[i_], &Asm[buf][(i_*256 + ldsbase)*8]); \
    _Pragma("unroll") \
    for (int i_=0;i_<4;i_++) \
      GLD_LDS16(bseg[i_], &Bsm[buf][(i_*256 + ldsbase)*8]); \
    _Pragma("unroll") \
    for (int i_=0;i_<4;i_++){ aseg[i_] += 64; bseg[i_] += 64; } \
  } while(0)

  STAGE(0);
  asm volatile("s_waitcnt vmcnt(0)" ::: "memory");
  __syncthreads();

  for (int t=0; t<nt; t++){
    int cur = t & 1;
    if (t+1 < nt) STAGE(cur^1);
    #pragma unroll
    for (int kc=0;kc<2;kc++){
      bf16x8 af[4], bfr[4];
      #pragma unroll
      for (int mi=0;mi<4;mi++){
        int r = wr*64 + mi*16 + lc;
        int s = kc*4 + lr;
        af[mi] = *(const bf16x8*)(&Asm[cur][r*64 + (s ^ (r&7))*8]);
      }
      #pragma unroll
      for (int ni=0;ni<4;ni++){
        int r = wc*64 + ni*16 + lc;
        int s = kc*4 + lr;
        bfr[ni] = *(const bf16x8*)(&Bsm[cur][r*64 + (s ^ (r&7))*8]);
      }
      #pragma unroll
      for (int mi=0;mi<4;mi++)
        #pragma unroll
        for (int ni=0;ni<4;ni++)
          acc[mi][ni] = __builtin_amdgcn_mfma_f32_16x16x32_bf16(af[mi], bfr[ni], acc[mi][ni], 0, 0, 0);
    }
    if (t+1 < nt) asm volatile("s_waitcnt vmcnt(0)" ::: "memory");
    __syncthreads();
  }
  #undef STAGE

  if (ACCUM){
    float* Cg = (float*)Cp + (long)g*cstride;
    #pragma unroll
    for (int ni=0;ni<4;ni++){
      int col = blockIdx.y*128 + wc*64 + ni*16 + lc;
      float bv = HASBIAS ? biasg[col] : 0.0f;
      #pragma unroll
      for (int mi=0;mi<4;mi++){
        int row = blockIdx.x*128 + wr*64 + mi*16 + lr*4;
        #pragma unroll
        for (int j=0;j<4;j++){
          float v = acc[mi][ni][j] + bv;
          if (GELU) v = gelu_f(v);
          Cg[(long)(row+j)*ldc + col] += v;
        }
      }
    }
  } else {
    __hip_bfloat16* Cg = (__hip_bfloat16*)Cp + (long)g*cstride;
    #pragma unroll
    for (int ni=0;ni<4;ni++){
      int col = blockIdx.y*128 + wc*64 + ni*16 + lc;
      float bv = HASBIAS ? biasg[col] : 0.0f;
      #pragma unroll
      for (int mi=0;mi<4;mi++){
        int row = blockIdx.x*128 + wr*64 + mi*16 + lr*4;
        #pragma unroll
        for (int j=0;j<4;j++){
          float v = acc[mi][ni][j] + bv;
          if (GELU) v = gelu_f(v);
          Cg[(long)(row+j)*ldc + col] = __float2bfloat16(v);
        }
      }
    }
  }
}

// K10: 8-head/8-slot attention; in-place on bf16 Q; K from transposed cache
__global__ __launch_bounds__(256) void attn_kernel(
    __hip_bfloat16* __restrict__ QO, const float* __restrict__ kvkT,
    const float* __restrict__ kvv, int l)
{
  __shared__ float q_sm[4][8][68];
  int w = threadIdx.x>>6, lane = threadIdx.x&63;
  long tg = (long)blockIdx.x*4 + w;
  int g = (int)(tg>>10); int b = g>>2, p = g&3;
  long kvbase = (long)((p*LL+l)*BB + b);
  const __hip_bfloat16* Q = QO + tg*INNER;
  #pragma unroll
  for (int i=0;i<8;i++) q_sm[w][i][lane] = __bfloat162float(Q[i*64+lane]);
  __syncthreads();
  int h = lane>>3, j = lane&7;
  const float* kp = kvkT + kvbase*4096 + h*512 + j;
  float acc=0.f;
  #pragma unroll
  for (int dh=0;dh<64;dh++) acc = fmaf(q_sm[w][h][dh], kp[dh*8], acc);
  acc *= SCALE;
  float mx = acc;
  mx = fmaxf(mx, __shfl_xor(mx,1));
  mx = fmaxf(mx, __shfl_xor(mx,2));
  mx = fmaxf(mx, __shfl_xor(mx,4));
  float e = __expf(acc-mx);
  float s = e;
  s += __shfl_xor(s,1); s += __shfl_xor(s,2); s += __shfl_xor(s,4);
  float a = e/s;
  float o[8] = {0,0,0,0,0,0,0,0};
  #pragma unroll
  for (int jj=0;jj<8;jj++){
    float aj = __shfl(a, (lane&56)+jj);
    const float* vp = kvv + (kvbase*NT + jj)*INNER + lane*8;
    #pragma unroll
    for (int qi=0;qi<8;qi++) o[qi] = fmaf(aj, vp[qi], o[qi]);
  }
  __hip_bfloat16* Op = QO + tg*INNER + lane*8;
  #pragma unroll
  for (int qi=0;qi<8;qi++) Op[qi] = __float2bfloat16(o[qi]);
}

// K11: scale by pw, final LN, scatter; 8 rows/block
__global__ __launch_bounds__(256) void final_kernel(
    const float* __restrict__ Xc, const int* __restrict__ cidx,
    const float* __restrict__ pw, const float* __restrict__ fln_g,
    const float* __restrict__ fln_b, float* __restrict__ out)
{
  long slot = (long)blockIdx.x*8 + (threadIdx.x>>5);
  int l32 = threadIdx.x & 31;
  int b = (int)(slot>>12);
  int p = (int)((slot>>10)&3);
  int i = cidx[slot];
  float pwv = pw[b*PP+p];
  const float* xr = Xc + slot*DD + l32*8;
  float4 v0 = *(const float4*)xr;
  float4 v1 = *(const float4*)(xr+4);
  float vv[8] = {v0.x,v0.y,v0.z,v0.w,v1.x,v1.y,v1.z,v1.w};
  #pragma unroll
  for (int k=0;k<8;k++) vv[k] *= pwv;
  float s = 0.f;
  #pragma unroll
  for (int k=0;k<8;k++) s += vv[k];
  #pragma unroll
  for (int mk=16; mk; mk>>=1) s += __shfl_xor(s, mk);
  float mu = s*(1.0f/256.0f);
  float q = 0.f;
  #pragma unroll
  for (int k=0;k<8;k++){ float d = vv[k]-mu; q += d*d; }
  #pragma unroll
  for (int mk=16; mk; mk>>=1) q += __shfl_xor(q, mk);
  float rs = rsqrtf(q*(1.0f/256.0f)+1e-5f);
  float* op = out + ((long)b*NN+i)*DD + l32*8;
  float4 o0, o1;
  o0.x = (vv[0]-mu)*rs*fln_g[l32*8+0]+fln_b[l32*8+0];
  o0.y = (vv[1]-mu)*rs*fln_g[l32*8+1]+fln_b[l32*8+1];
  o0.z = (vv[2]-mu)*rs*fln_g[l32*8+2]+fln_b[l32*8+2];
  o0.w = (vv[3]-mu)*rs*fln_g[l32*8+3]+fln_b[l32*8+3];
  o1.x = (vv[4]-mu)*rs*fln_g[l32*8+4]+fln_b[l32*8+4];
  o1.y = (vv[5]-mu)*rs*fln_g[l32*8+5]+fln_b[l32*8+5];
  o1.z = (vv[6]-mu)*rs*fln_g[l32*8+6]+fln_b[l32*8+6];
  o1.w = (vv[7]-mu)*rs*fln_g[l32*8+7]+fln_b[l32*8+7];
  *(float4*)op = o0;
  *(float4*)(op+4) = o1;
}

extern "C" void kernel_launch(void* const* d_in, const int* in_sizes, int n_in,
                              void* d_out, int out_size, void* d_ws, size_t ws_size,
                              hipStream_t stream)
{
  (void)in_sizes; (void)n_in; (void)out_size; (void)ws_size;
  const float* x     =(const float*)d_in[0];
  const float* m     =(const float*)d_in[1];
  const float* proj_w=(const float*)d_in[2];
  const float* proj_b=(const float*)d_in[3];
  const float* lnp_g =(const float*)d_in[4];
  const float* lnp_b =(const float*)d_in[5];
  const float* sq_w  =(const float*)d_in[6];
  const float* sq_b  =(const float*)d_in[7];
  const float* sk_w  =(const float*)d_in[8];
  const float* sk_b  =(const float*)d_in[9];
  const float* sv_w  =(const float*)d_in[10];
  const float* sv_b  =(const float*)d_in[11];
  const float* an_g  =(const float*)d_in[12];
  const float* an_b  =(const float*)d_in[13];
  const float* wq    =(const float*)d_in[14];
  const float* wk    =(const float*)d_in[15];
  const float* wv    =(const float*)d_in[16];
  const float* wo    =(const float*)d_in[17];
  const float* wo_b  =(const float*)d_in[18];
  const float* fn_g  =(const float*)d_in[19];
  const float* fn_b  =(const float*)d_in[20];
  const float* w1    =(const float*)d_in[21];
  const float* b1    =(const float*)d_in[22];
  const float* w2    =(const float*)d_in[23];
  const float* b2    =(const float*)d_in[24];
  const float* fln_g =(const float*)d_in[25];
  const float* fln_b =(const float*)d_in[26];
  float* out = (float*)d_out;

  float* ws = (float*)d_ws;
  float* tokens = ws;  ws += 4194304;   // 16 MB; first half of actF alias
  float* actQf  = ws;  ws += 4194304;   // actQ bf16 (16384x512); 2nd half of actF
  float* Xc     = ws;  ws += 4194304;   // fp32 residual
  float* actAf  = ws;  ws += 2097152;   // actA bf16 (16384x256)
  float* wqTf   = ws;  ws += 524288;
  float* woTf   = ws;  ws += 524288;
  float* w1Tf   = ws;  ws += 1048576;
  float* w2Tf   = ws;  ws += 1048576;
  float* kvkT   = ws;  ws += 131072;
  float* kvv    = ws;  ws += 131072;
  float* ksc    = ws;  ws += 8192;
  float* vsc    = ws;  ws += 64;
  float* kk2    = ws;  ws += 8192;
  float* kb     = ws;  ws += 32;
  float* scores = ws;  ws += 16384;
  float* pw     = ws;  ws += 16;
  int* rank     = (int*)ws;  ws += 16384;
  int* cidx     = (int*)ws;  ws += 16384;

  __hip_bfloat16* actA = (__hip_bfloat16*)actAf;
  __hip_bfloat16* actQ = (__hip_bfloat16*)actQf;
  __hip_bfloat16* actF = (__hip_bfloat16*)tokens;
  __hip_bfloat16* wqT  = (__hip_bfloat16*)wqTf;
  __hip_bfloat16* woT  = (__hip_bfloat16*)woTf;
  __hip_bfloat16* w1T  = (__hip_bfloat16*)w1Tf;
  __hip_bfloat16* w2T  = (__hip_bfloat16*)w2Tf;

  hipMemsetAsync(rank, 0, BB*NN*sizeof(int), stream);
  scorer_kv_kernel<<<32,256,0,stream>>>(m, sk_w, sk_b, sv_w, sv_b, ksc, vsc);
  kk2_kernel<<<32,256,0,stream>>>(sq_w, sq_b, ksc, kk2, kb);
  proj_ln_score_kernel<<<1024,256,0,stream>>>(x, proj_w, proj_b, lnp_g, lnp_b,
                                              kk2, kb, vsc, tokens, scores);
  rank_partial_kernel<<<1024,256,0,stream>>>(scores, rank);
  rank_finalize_kernel<<<64,256,0,stream>>>(rank, cidx);
  pscore_pw_kernel<<<1,1024,0,stream>>>(scores, cidx, pw);
  kv_kernel<<<256,512,0,stream>>>(m, an_g, an_b, wk, wv, kvkT, kvv);
  wconv_all_kernel<<<1536,256,0,stream>>>(wq, wo, w1, w2, wqT, woT, w1T, w2T);
  gather_ln_kernel<<<2048,256,0,stream>>>(tokens, cidx, Xc, actA, an_g, an_b);

  for (int l=0;l<LL;l++){
    if (l > 0)
      ln_rows_kernel<<<2048,256,0,stream>>>(Xc, actA, an_g + l*DD, an_b + l*DD);
    // Q = xn @ wq[p,l]   grid (rows, cols, g)
    mfma_gemm<false,false,false><<<dim3(8,4,16),256,0,stream>>>(
        actA, (long)SS*DD, DD, wqT + (long)l*INNER*DD, (long)LL*INNER*DD,
        nullptr, 0, actQ, INNER, (long)SS*INNER);
    attn_kernel<<<4096,256,0,stream>>>(actQ, kvkT, kvv, l);
    // Xc += AO @ wo[p,l] + wo_b
    mfma_gemm<true,false,true><<<dim3(8,2,16),256,0,stream>>>(
        actQ, (long)SS*INNER, INNER, woT + (long)l*DD*INNER, (long)LL*DD*INNER,
        wo_b + l*DD, LL*DD, Xc, DD, (long)SS*DD);
    ln_rows_kernel<<<2048,256,0,stream>>>(Xc, actA, fn_g + l*DD, fn_b + l*DD);
    // F = gelu(h @ w1 + b1)
    mfma_gemm<true,true,false><<<dim3(8,8,16),256,0,stream>>>(
        actA, (long)SS*DD, DD, w1T + (long)l*FFD*DD, (long)LL*FFD*DD,
        b1 + l*FFD, LL*FFD, actF, FFD, (long)SS*FFD);
    // Xc += F @ w2 + b2
    mfma_gemm<true,false,true><<<dim3(8,2,16),256,0,stream>>>(
        actF, (long)SS*FFD, FFD, w2T + (long)l*DD*FFD, (long)LL*DD*FFD,
        b2 + l*DD, LL*DD, Xc, DD, (long)SS*DD);
  }
  final_kernel<<<2048,256,0,stream>>>(Xc, cidx, pw, fln_g, fln_b, out);
}